// Round 3
// baseline (11835.789 us; speedup 1.0000x reference)
//
#include <hip/hip_runtime.h>
#include <hip/hip_bf16.h>
#include <cstddef>

#define BD    2048
#define NF    32
#define DIMC  64
#define HEADS 8
#define DROW  2048
#define LNEPS 1e-5f

typedef __hip_bfloat16 bf16;

// dtype-flagged input load: flag=1 -> buffer is bf16, flag=0 -> fp32
__device__ inline float ldin(const void* p, size_t i, int bf) {
    if (bf) return __bfloat162float(((const bf16*)p)[i]);
    return ((const float*)p)[i];
}

__device__ inline float gelu_exact(float x) {
    return 0.5f * x * (1.0f + erff(x * 0.70710678118654752f));
}

// ---------------- dtype detector ----------------
// x ~ N(0,1), 2,097,152 elems. Sample even-indexed bf16 slots: if buffer is
// bf16 all exponents are plausible; if fp32 the even slots are low-mantissa
// garbage (~15% plausible). flag: 1=bf16, 0=fp32.
__global__ __launch_bounds__(64) void k_detect(const void* __restrict__ x,
                                               int* __restrict__ flag) {
    int i = threadIdx.x;
    size_t idx = (size_t)(2 * i) * 16384;
    unsigned short u = ((const unsigned short*)x)[idx];
    int e = (u >> 7) & 0xFF;
    int plausible = (e == 0) || (e >= 96 && e <= 132);
    unsigned long long m = __ballot(plausible);
    if (i == 0) *flag = (__popcll(m) >= 48) ? 1 : 0;
}

// ---------------- concat [x, x_cont] -> X (fp32) ----------------
__global__ __launch_bounds__(256) void k_concat(const void* __restrict__ x,
                                                const void* __restrict__ xc,
                                                float* __restrict__ X,
                                                const int* __restrict__ flag) {
    const int bf = *flag;
    int i = blockIdx.x * 256 + threadIdx.x;
    int d = i & 63;
    int f = (i >> 6) & 31;
    int b = i >> 11;
    float v = (f < 16) ? ldin(x,  ((size_t)b * 16 + f) * 64 + d, bf)
                       : ldin(xc, ((size_t)b * 16 + (f - 16)) * 64 + d, bf);
    X[i] = v;
}

// ---------------- LayerNorm over last-64 ----------------
__global__ __launch_bounds__(256) void k_ln64(const float* __restrict__ in,
                                              float* __restrict__ out,
                                              const void* __restrict__ g,
                                              const void* __restrict__ b,
                                              size_t eoff,
                                              const int* __restrict__ flag) {
    const int bf = *flag;
    int row  = blockIdx.x * 4 + (threadIdx.x >> 6);
    int lane = threadIdx.x & 63;
    float v = in[(size_t)row * 64 + lane];
    float s = v;
    #pragma unroll
    for (int off = 32; off; off >>= 1) s += __shfl_xor(s, off);
    float mean = s * (1.0f / 64.0f);
    float dx = v - mean;
    float s2 = dx * dx;
    #pragma unroll
    for (int off = 32; off; off >>= 1) s2 += __shfl_xor(s2, off);
    float inv = rsqrtf(s2 * (1.0f / 64.0f) + LNEPS);
    out[(size_t)row * 64 + lane] =
        dx * inv * ldin(g, eoff + lane, bf) + ldin(b, eoff + lane, bf);
}

// ---------------- LayerNorm over 2048 ----------------
__global__ __launch_bounds__(256) void k_ln_row(const float* __restrict__ in,
                                                float* __restrict__ out,
                                                const void* __restrict__ g,
                                                const void* __restrict__ b,
                                                size_t eoff,
                                                const int* __restrict__ flag) {
    const int bf = *flag;
    const int row = blockIdx.x, tid = threadIdx.x;
    __shared__ float red[4];
    const float* r = in + (size_t)row * DROW;
    float v[8];
    float s = 0.f;
    #pragma unroll
    for (int i = 0; i < 8; ++i) { v[i] = r[tid + i * 256]; s += v[i]; }
    #pragma unroll
    for (int off = 32; off; off >>= 1) s += __shfl_xor(s, off);
    if ((tid & 63) == 0) red[tid >> 6] = s;
    __syncthreads();
    float mean = (red[0] + red[1] + red[2] + red[3]) * (1.0f / DROW);
    __syncthreads();
    float s2 = 0.f;
    #pragma unroll
    for (int i = 0; i < 8; ++i) { float dx = v[i] - mean; s2 += dx * dx; }
    #pragma unroll
    for (int off = 32; off; off >>= 1) s2 += __shfl_xor(s2, off);
    if ((tid & 63) == 0) red[tid >> 6] = s2;
    __syncthreads();
    float inv = rsqrtf((red[0] + red[1] + red[2] + red[3]) * (1.0f / DROW) + LNEPS);
    #pragma unroll
    for (int i = 0; i < 8; ++i) {
        int j = tid + i * 256;
        out[(size_t)row * DROW + j] =
            (v[i] - mean) * inv * ldin(g, eoff + j, bf) + ldin(b, eoff + j, bf);
    }
}

// ---------------- ACC = XN + bias ----------------
__global__ __launch_bounds__(256) void k_bias_init(const float* __restrict__ XN,
                                                   const void* __restrict__ bias,
                                                   float* __restrict__ ACC,
                                                   size_t eoff,
                                                   const int* __restrict__ flag) {
    const int bf = *flag;
    int i = blockIdx.x * 256 + threadIdx.x;
    ACC[i] = XN[i] + ldin(bias, eoff + (i & 63), bf);
}

// ---------------- fused col attention, one block per (sample, head) ----------------
__global__ __launch_bounds__(256) void k_col_attn(const float* __restrict__ XN,
                                                  const void* __restrict__ wqkv,
                                                  const void* __restrict__ wo,
                                                  float* __restrict__ ACC,
                                                  size_t oqkv, size_t owo,
                                                  const int* __restrict__ flag) {
    const int bf = *flag;
    const int b = blockIdx.x, h = blockIdx.y, tid = threadIdx.x;
    __shared__ float xs[32][64];
    __shared__ float qs[32][64];
    __shared__ float ks[32][64];
    __shared__ float vs[32][64];
    __shared__ float ss[32][32];
    __shared__ float ws[64 * 64];

    const float* xrow = XN + (size_t)b * DROW;
    for (int i = tid; i < 2048; i += 256) xs[i >> 6][i & 63] = xrow[i];

    for (int m = 0; m < 3; ++m) {
        __syncthreads();
        for (int i = tid; i < 4096; i += 256)
            ws[i] = ldin(wqkv, oqkv + (size_t)(i >> 6) * 1536 + m * 512 + h * 64 + (i & 63), bf);
        __syncthreads();
        float (*tgt)[64] = (m == 0) ? qs : (m == 1) ? ks : vs;
        for (int e = tid; e < 2048; e += 256) {
            int r = e >> 6, c = e & 63;
            float acc = 0.f;
            for (int k = 0; k < 64; ++k) acc += xs[r][k] * ws[k * 64 + c];
            tgt[r][c] = acc;
        }
    }
    __syncthreads();

    for (int e = tid; e < 1024; e += 256) {
        int i = e >> 5, j = e & 31;
        float acc = 0.f;
        for (int d = 0; d < 64; ++d) acc += qs[i][d] * ks[j][d];
        ss[i][j] = acc * 0.125f;
    }
    __syncthreads();

    if (tid < 32) {
        float mx = -1e30f;
        for (int j = 0; j < 32; ++j) mx = fmaxf(mx, ss[tid][j]);
        float s = 0.f;
        for (int j = 0; j < 32; ++j) { float e = __expf(ss[tid][j] - mx); ss[tid][j] = e; s += e; }
        float inv = 1.0f / s;
        for (int j = 0; j < 32; ++j) ss[tid][j] *= inv;
    }
    __syncthreads();

    for (int e = tid; e < 2048; e += 256) {
        int r = e >> 6, c = e & 63;
        float acc = 0.f;
        for (int j = 0; j < 32; ++j) acc += ss[r][j] * vs[j][c];
        xs[r][c] = acc;
    }
    __syncthreads();

    for (int i = tid; i < 4096; i += 256)
        ws[i] = ldin(wo, owo + (size_t)(h * 64 + (i >> 6)) * 64 + (i & 63), bf);
    __syncthreads();

    for (int e = tid; e < 2048; e += 256) {
        int r = e >> 6, c = e & 63;
        float acc = 0.f;
        for (int k = 0; k < 64; ++k) acc += xs[r][k] * ws[k * 64 + c];
        atomicAdd(&ACC[(size_t)b * DROW + r * 64 + c], acc);
    }
}

// ---------------- fused col GEGLU MLP, one block per sample ----------------
__global__ __launch_bounds__(256) void k_col_mlp(const float* __restrict__ XN,
                                                 const void* __restrict__ w1,
                                                 const void* __restrict__ b1,
                                                 const void* __restrict__ w2,
                                                 const void* __restrict__ b2,
                                                 float* __restrict__ X,
                                                 size_t ow1, size_t ob1,
                                                 size_t ow2, size_t ob2,
                                                 const int* __restrict__ flag) {
    const int bf = *flag;
    const int b = blockIdx.x, tid = threadIdx.x;
    __shared__ float xs[32][64];
    __shared__ float ps[32][256];
    const float* xrow = XN + (size_t)b * DROW;
    for (int i = tid; i < 2048; i += 256) xs[i >> 6][i & 63] = xrow[i];
    __syncthreads();

    float a[32], g[32];
    #pragma unroll
    for (int r = 0; r < 32; ++r) { a[r] = 0.f; g[r] = 0.f; }
    for (int k = 0; k < 64; ++k) {
        float wa = ldin(w1, ow1 + k * 512 + tid, bf);
        float wg = ldin(w1, ow1 + k * 512 + 256 + tid, bf);
        #pragma unroll
        for (int r = 0; r < 32; ++r) { float xv = xs[r][k]; a[r] += xv * wa; g[r] += xv * wg; }
    }
    float ba = ldin(b1, ob1 + tid, bf), bg = ldin(b1, ob1 + 256 + tid, bf);
    #pragma unroll
    for (int r = 0; r < 32; ++r)
        ps[r][tid] = (a[r] + ba) * gelu_exact(g[r] + bg);
    __syncthreads();

    for (int e = tid; e < 2048; e += 256) {
        int r = e >> 6, c = e & 63;
        float acc = 0.f;
        for (int j = 0; j < 256; ++j) acc += ps[r][j] * ldin(w2, ow2 + j * 64 + c, bf);
        acc += ldin(b2, ob2 + c, bf) + xs[r][c];
        X[(size_t)b * DROW + e] = acc;
    }
}

// ---------------- generic tiled GEMM ----------------
// A fp32 MxK row-major. B: NN -> KxN, NT -> NxK. BIN: B/bias are flagged inputs.
template <bool NT, bool BIN>
__global__ __launch_bounds__(256) void k_gemm(int M, int N, int K,
                                              const float* __restrict__ A, int lda, long long sA,
                                              const void* __restrict__ Bm, size_t bEoff, int ldb, long long sB,
                                              float* __restrict__ C, int ldc, long long sC,
                                              float alpha,
                                              const void* __restrict__ bias, size_t biasEoff,
                                              const float* __restrict__ addend, int ldadd,
                                              const int* __restrict__ flag) {
    const int bf = BIN ? *flag : 0;
    const int bz = blockIdx.z;
    A += (size_t)bz * sA;
    C += (size_t)bz * sC;
    const size_t bOff = bEoff + (size_t)bz * sB;
    const int n0 = blockIdx.x * 64, m0 = blockIdx.y * 64;
    const int tid = threadIdx.x, tx = tid & 15, ty = tid >> 4;
    __shared__ float As[16][65];
    __shared__ float Bs[16][65];
    float acc[4][4] = {};
    for (int k0 = 0; k0 < K; k0 += 16) {
        for (int i = tid; i < 1024; i += 256) {
            int mm = i >> 4, kk = i & 15;
            As[kk][mm] = A[(size_t)(m0 + mm) * lda + k0 + kk];
        }
        if (NT) {
            for (int i = tid; i < 1024; i += 256) {
                int nn = i >> 4, kk = i & 15;
                size_t idx = bOff + (size_t)(n0 + nn) * ldb + k0 + kk;
                Bs[kk][nn] = BIN ? ldin(Bm, idx, bf) : ((const float*)Bm)[idx];
            }
        } else {
            for (int i = tid; i < 1024; i += 256) {
                int kk = i >> 6, nn = i & 63;
                size_t idx = bOff + (size_t)(k0 + kk) * ldb + n0 + nn;
                Bs[kk][nn] = BIN ? ldin(Bm, idx, bf) : ((const float*)Bm)[idx];
            }
        }
        __syncthreads();
        #pragma unroll
        for (int kk = 0; kk < 16; ++kk) {
            float ra[4], rb[4];
            #pragma unroll
            for (int a = 0; a < 4; ++a) ra[a] = As[kk][ty + a * 16];
            #pragma unroll
            for (int b = 0; b < 4; ++b) rb[b] = Bs[kk][tx + b * 16];
            #pragma unroll
            for (int a = 0; a < 4; ++a)
                #pragma unroll
                for (int b = 0; b < 4; ++b) acc[a][b] += ra[a] * rb[b];
        }
        __syncthreads();
    }
    #pragma unroll
    for (int a = 0; a < 4; ++a) {
        int m = m0 + ty + a * 16;
        #pragma unroll
        for (int b = 0; b < 4; ++b) {
            int n = n0 + tx + b * 16;
            float v = acc[a][b] * alpha;
            if (bias)   v += ldin(bias, biasEoff + n, bf);
            if (addend) v += addend[(size_t)m * ldadd + n];
            C[(size_t)m * ldc + n] = v;
        }
    }
}

// ---------------- softmax over rows of 2048 (in-place) ----------------
__global__ __launch_bounds__(256) void k_softmax(float* __restrict__ S) {
    const int row = blockIdx.x, tid = threadIdx.x;
    float* r = S + (size_t)row * 2048;
    __shared__ float red[4];
    float v[8];
    float mx = -1e30f;
    #pragma unroll
    for (int i = 0; i < 8; ++i) { v[i] = r[tid + i * 256]; mx = fmaxf(mx, v[i]); }
    #pragma unroll
    for (int off = 32; off; off >>= 1) mx = fmaxf(mx, __shfl_xor(mx, off));
    if ((tid & 63) == 0) red[tid >> 6] = mx;
    __syncthreads();
    mx = fmaxf(fmaxf(red[0], red[1]), fmaxf(red[2], red[3]));
    __syncthreads();
    float s = 0.f;
    #pragma unroll
    for (int i = 0; i < 8; ++i) { v[i] = __expf(v[i] - mx); s += v[i]; }
    #pragma unroll
    for (int off = 32; off; off >>= 1) s += __shfl_xor(s, off);
    if ((tid & 63) == 0) red[tid >> 6] = s;
    __syncthreads();
    float inv = 1.0f / (red[0] + red[1] + red[2] + red[3]);
    #pragma unroll
    for (int i = 0; i < 8; ++i) r[tid + i * 256] = v[i] * inv;
}

// ---------------- GEGLU elementwise ----------------
__global__ __launch_bounds__(256) void k_geglu(const float* __restrict__ H,
                                               float* __restrict__ P) {
    int i = blockIdx.x * 256 + threadIdx.x;
    int r = i >> 10, j = i & 1023;
    float a = H[(size_t)r * 2048 + j];
    float g = H[(size_t)r * 2048 + 1024 + j];
    P[i] = a * gelu_exact(g);
}

// ---------------- final cast fp32 -> output dtype ----------------
__global__ __launch_bounds__(256) void k_cast_out(const float* __restrict__ X,
                                                  void* __restrict__ out,
                                                  const int* __restrict__ flag) {
    const int bf = *flag;
    int i = blockIdx.x * 256 + threadIdx.x;
    if (bf) ((bf16*)out)[i] = __float2bfloat16(X[i]);
    else    ((float*)out)[i] = X[i];
}

// =====================================================================
extern "C" void kernel_launch(void* const* d_in, const int* in_sizes, int n_in,
                              void* d_out, int out_size, void* d_ws, size_t ws_size,
                              hipStream_t stream) {
    const void* x       = d_in[0];
    const void* x_cont  = d_in[1];
    const void* c_ln1_g = d_in[2];
    const void* c_ln1_b = d_in[3];
    const void* c_wqkv  = d_in[4];
    const void* c_wo_w  = d_in[5];
    const void* c_wo_b  = d_in[6];
    const void* c_ln2_g = d_in[7];
    const void* c_ln2_b = d_in[8];
    const void* c_w1    = d_in[9];
    const void* c_b1    = d_in[10];
    const void* c_w2    = d_in[11];
    const void* c_b2    = d_in[12];
    const void* r_ln1_g = d_in[13];
    const void* r_ln1_b = d_in[14];
    const void* r_wqkv  = d_in[15];
    const void* r_wo_w  = d_in[16];
    const void* r_wo_b  = d_in[17];
    const void* r_ln2_g = d_in[18];
    const void* r_ln2_b = d_in[19];
    const void* r_w1    = d_in[20];
    const void* r_b1    = d_in[21];
    const void* r_w2    = d_in[22];
    const void* r_b2    = d_in[23];

    const size_t NX = (size_t)BD * NF * DIMC;        // 4,194,304
    float* X   = (float*)d_ws;
    float* XN  = X   + NX;
    float* ACC = XN  + NX;
    float* QKV = ACC + NX;                           // 2048 x 1536
    float* O   = QKV + (size_t)2048 * 1536;          // 2048 x 512
    float* S   = O   + (size_t)2048 * 512;           // 8 x 2048 x 2048
    float* H   = S;
    float* P   = S + NX;
    float* END = S + (size_t)8 * 2048 * 2048;
    int*  flag = (int*)END;
    const size_t need = ((size_t)(END - X)) * sizeof(float) + 64;
    if (ws_size < need) return;

    k_detect<<<1, 64, 0, stream>>>(x, flag);
    k_concat<<<16384, 256, 0, stream>>>(x, x_cont, X, flag);

    for (int d = 0; d < 4; ++d) {
        // ---- col block ----
        k_ln64<<<16384, 256, 0, stream>>>(X, XN, c_ln1_g, c_ln1_b, (size_t)d * 64, flag);
        k_bias_init<<<16384, 256, 0, stream>>>(XN, c_wo_b, ACC, (size_t)d * 64, flag);
        k_col_attn<<<dim3(BD, HEADS), 256, 0, stream>>>(
            XN, c_wqkv, c_wo_w, ACC,
            (size_t)d * 64 * 1536, (size_t)d * 512 * 64, flag);
        k_ln64<<<16384, 256, 0, stream>>>(ACC, XN, c_ln2_g, c_ln2_b, (size_t)d * 64, flag);
        k_col_mlp<<<BD, 256, 0, stream>>>(
            XN, c_w1, c_b1, c_w2, c_b2, X,
            (size_t)d * 64 * 512, (size_t)d * 512,
            (size_t)d * 256 * 64, (size_t)d * 64, flag);

        // ---- row block ----
        k_ln_row<<<BD, 256, 0, stream>>>(X, XN, r_ln1_g, r_ln1_b, (size_t)d * DROW, flag);
        // QKV = XN @ r_wqkv
        k_gemm<false, true><<<dim3(24, 32, 1), 256, 0, stream>>>(
            2048, 1536, 2048, XN, 2048, 0,
            r_wqkv, (size_t)d * 2048 * 1536, 1536, 0,
            QKV, 1536, 0, 1.0f, nullptr, 0, nullptr, 0, flag);
        // S_h = Q_h @ K_h^T * 0.125
        k_gemm<true, false><<<dim3(32, 32, 8), 256, 0, stream>>>(
            2048, 2048, 64, QKV, 1536, 64,
            QKV + 512, 0, 1536, 64,
            S, 2048, (long long)2048 * 2048, 0.125f, nullptr, 0, nullptr, 0, flag);
        k_softmax<<<16384, 256, 0, stream>>>(S);
        // O_h = S_h @ V_h
        k_gemm<false, false><<<dim3(1, 32, 8), 256, 0, stream>>>(
            2048, 64, 2048, S, 2048, (long long)2048 * 2048,
            QKV + 1024, 0, 1536, 64,
            O, 512, 64, 1.0f, nullptr, 0, nullptr, 0, flag);
        // ACC = O @ r_wo_w + r_wo_b + XN
        k_gemm<false, true><<<dim3(32, 32, 1), 256, 0, stream>>>(
            2048, 2048, 512, O, 512, 0,
            r_wo_w, (size_t)d * 512 * 2048, 2048, 0,
            ACC, 2048, 0, 1.0f, r_wo_b, (size_t)d * DROW, XN, 2048, flag);
        k_ln_row<<<BD, 256, 0, stream>>>(ACC, XN, r_ln2_g, r_ln2_b, (size_t)d * DROW, flag);
        // H = XN @ r_w1 + r_b1
        k_gemm<false, true><<<dim3(32, 32, 1), 256, 0, stream>>>(
            2048, 2048, 2048, XN, 2048, 0,
            r_w1, (size_t)d * 2048 * 2048, 2048, 0,
            H, 2048, 0, 1.0f, r_b1, (size_t)d * 2048, nullptr, 0, flag);
        k_geglu<<<8192, 256, 0, stream>>>(H, P);
        // X = P @ r_w2 + r_b2 + XN
        k_gemm<false, true><<<dim3(32, 32, 1), 256, 0, stream>>>(
            2048, 2048, 1024, P, 1024, 0,
            r_w2, (size_t)d * 1024 * 2048, 2048, 0,
            X, 2048, 0, 1.0f, r_b2, (size_t)d * DROW, XN, 2048, flag);
    }

    k_cast_out<<<16384, 256, 0, stream>>>(X, d_out, flag);
}

// Round 4
// 6696.925 us; speedup vs baseline: 1.7673x; 1.7673x over previous
//
#include <hip/hip_runtime.h>
#include <hip/hip_bf16.h>
#include <cstddef>

#define BD    2048
#define NF    32
#define DIMC  64
#define HEADS 8
#define DROW  2048
#define LNEPS 1e-5f

typedef __hip_bfloat16 bf16;
typedef __attribute__((ext_vector_type(8))) short short8;
typedef __attribute__((ext_vector_type(4))) float f32x4;

// dtype-flagged external-input load: flag=1 -> bf16, flag=0 -> fp32
__device__ inline float ldin(const void* p, size_t i, int bf) {
    if (bf) return __bfloat162float(((const bf16*)p)[i]);
    return ((const float*)p)[i];
}

__device__ inline float gelu_exact(float x) {
    return 0.5f * x * (1.0f + erff(x * 0.70710678118654752f));
}

// ---------------- dtype detector (external inputs fp32 vs bf16) ----------------
__global__ __launch_bounds__(64) void k_detect(const void* __restrict__ x,
                                               int* __restrict__ flag) {
    int i = threadIdx.x;
    size_t idx = (size_t)(2 * i) * 16384;
    unsigned short u = ((const unsigned short*)x)[idx];
    int e = (u >> 7) & 0xFF;
    int plausible = (e == 0) || (e >= 96 && e <= 132);
    unsigned long long m = __ballot(plausible);
    if (i == 0) *flag = (__popcll(m) >= 48) ? 1 : 0;
}

// ---------------- concat [x, x_cont] -> X (fp32) ----------------
__global__ __launch_bounds__(256) void k_concat(const void* __restrict__ x,
                                                const void* __restrict__ xc,
                                                float* __restrict__ X,
                                                const int* __restrict__ flag) {
    const int bf = *flag;
    int i = blockIdx.x * 256 + threadIdx.x;
    int d = i & 63;
    int f = (i >> 6) & 31;
    int b = i >> 11;
    float v = (f < 16) ? ldin(x,  ((size_t)b * 16 + f) * 64 + d, bf)
                       : ldin(xc, ((size_t)b * 16 + (f - 16)) * 64 + d, bf);
    X[i] = v;
}

// ---------------- LayerNorm over last-64 ----------------
__global__ __launch_bounds__(256) void k_ln64(const float* __restrict__ in,
                                              float* __restrict__ out,
                                              const void* __restrict__ g,
                                              const void* __restrict__ b,
                                              size_t eoff,
                                              const int* __restrict__ flag) {
    const int bf = *flag;
    int row  = blockIdx.x * 4 + (threadIdx.x >> 6);
    int lane = threadIdx.x & 63;
    float v = in[(size_t)row * 64 + lane];
    float s = v;
    #pragma unroll
    for (int off = 32; off; off >>= 1) s += __shfl_xor(s, off);
    float mean = s * (1.0f / 64.0f);
    float dx = v - mean;
    float s2 = dx * dx;
    #pragma unroll
    for (int off = 32; off; off >>= 1) s2 += __shfl_xor(s2, off);
    float inv = rsqrtf(s2 * (1.0f / 64.0f) + LNEPS);
    out[(size_t)row * 64 + lane] =
        dx * inv * ldin(g, eoff + lane, bf) + ldin(b, eoff + lane, bf);
}

// ---------------- LayerNorm over 2048 ----------------
__global__ __launch_bounds__(256) void k_ln_row(const float* __restrict__ in,
                                                float* __restrict__ out,
                                                const void* __restrict__ g,
                                                const void* __restrict__ b,
                                                size_t eoff,
                                                const int* __restrict__ flag) {
    const int bf = *flag;
    const int row = blockIdx.x, tid = threadIdx.x;
    __shared__ float red[4];
    const float* r = in + (size_t)row * DROW;
    float v[8];
    float s = 0.f;
    #pragma unroll
    for (int i = 0; i < 8; ++i) { v[i] = r[tid + i * 256]; s += v[i]; }
    #pragma unroll
    for (int off = 32; off; off >>= 1) s += __shfl_xor(s, off);
    if ((tid & 63) == 0) red[tid >> 6] = s;
    __syncthreads();
    float mean = (red[0] + red[1] + red[2] + red[3]) * (1.0f / DROW);
    __syncthreads();
    float s2 = 0.f;
    #pragma unroll
    for (int i = 0; i < 8; ++i) { float dx = v[i] - mean; s2 += dx * dx; }
    #pragma unroll
    for (int off = 32; off; off >>= 1) s2 += __shfl_xor(s2, off);
    if ((tid & 63) == 0) red[tid >> 6] = s2;
    __syncthreads();
    float inv = rsqrtf((red[0] + red[1] + red[2] + red[3]) * (1.0f / DROW) + LNEPS);
    #pragma unroll
    for (int i = 0; i < 8; ++i) {
        int j = tid + i * 256;
        out[(size_t)row * DROW + j] =
            (v[i] - mean) * inv * ldin(g, eoff + j, bf) + ldin(b, eoff + j, bf);
    }
}

// ---------------- ACC = XN + bias ----------------
__global__ __launch_bounds__(256) void k_bias_init(const float* __restrict__ XN,
                                                   const void* __restrict__ bias,
                                                   float* __restrict__ ACC,
                                                   size_t eoff,
                                                   const int* __restrict__ flag) {
    const int bf = *flag;
    int i = blockIdx.x * 256 + threadIdx.x;
    ACC[i] = XN[i] + ldin(bias, eoff + (i & 63), bf);
}

// ---------------- fused col attention (unchanged this round) ----------------
__global__ __launch_bounds__(256) void k_col_attn(const float* __restrict__ XN,
                                                  const void* __restrict__ wqkv,
                                                  const void* __restrict__ wo,
                                                  float* __restrict__ ACC,
                                                  size_t oqkv, size_t owo,
                                                  const int* __restrict__ flag) {
    const int bf = *flag;
    const int b = blockIdx.x, h = blockIdx.y, tid = threadIdx.x;
    __shared__ float xs[32][64];
    __shared__ float qs[32][64];
    __shared__ float ks[32][64];
    __shared__ float vs[32][64];
    __shared__ float ss[32][32];
    __shared__ float ws[64 * 64];

    const float* xrow = XN + (size_t)b * DROW;
    for (int i = tid; i < 2048; i += 256) xs[i >> 6][i & 63] = xrow[i];

    for (int m = 0; m < 3; ++m) {
        __syncthreads();
        for (int i = tid; i < 4096; i += 256)
            ws[i] = ldin(wqkv, oqkv + (size_t)(i >> 6) * 1536 + m * 512 + h * 64 + (i & 63), bf);
        __syncthreads();
        float (*tgt)[64] = (m == 0) ? qs : (m == 1) ? ks : vs;
        for (int e = tid; e < 2048; e += 256) {
            int r = e >> 6, c = e & 63;
            float acc = 0.f;
            for (int k = 0; k < 64; ++k) acc += xs[r][k] * ws[k * 64 + c];
            tgt[r][c] = acc;
        }
    }
    __syncthreads();

    for (int e = tid; e < 1024; e += 256) {
        int i = e >> 5, j = e & 31;
        float acc = 0.f;
        for (int d = 0; d < 64; ++d) acc += qs[i][d] * ks[j][d];
        ss[i][j] = acc * 0.125f;
    }
    __syncthreads();

    if (tid < 32) {
        float mx = -1e30f;
        for (int j = 0; j < 32; ++j) mx = fmaxf(mx, ss[tid][j]);
        float s = 0.f;
        for (int j = 0; j < 32; ++j) { float e = __expf(ss[tid][j] - mx); ss[tid][j] = e; s += e; }
        float inv = 1.0f / s;
        for (int j = 0; j < 32; ++j) ss[tid][j] *= inv;
    }
    __syncthreads();

    for (int e = tid; e < 2048; e += 256) {
        int r = e >> 6, c = e & 63;
        float acc = 0.f;
        for (int j = 0; j < 32; ++j) acc += ss[r][j] * vs[j][c];
        xs[r][c] = acc;
    }
    __syncthreads();

    for (int i = tid; i < 4096; i += 256)
        ws[i] = ldin(wo, owo + (size_t)(h * 64 + (i >> 6)) * 64 + (i & 63), bf);
    __syncthreads();

    for (int e = tid; e < 2048; e += 256) {
        int r = e >> 6, c = e & 63;
        float acc = 0.f;
        for (int k = 0; k < 64; ++k) acc += xs[r][k] * ws[k * 64 + c];
        atomicAdd(&ACC[(size_t)b * DROW + r * 64 + c], acc);
    }
}

// ---------------- fused col GEGLU MLP (unchanged this round) ----------------
__global__ __launch_bounds__(256) void k_col_mlp(const float* __restrict__ XN,
                                                 const void* __restrict__ w1,
                                                 const void* __restrict__ b1,
                                                 const void* __restrict__ w2,
                                                 const void* __restrict__ b2,
                                                 float* __restrict__ X,
                                                 size_t ow1, size_t ob1,
                                                 size_t ow2, size_t ob2,
                                                 const int* __restrict__ flag) {
    const int bf = *flag;
    const int b = blockIdx.x, tid = threadIdx.x;
    __shared__ float xs[32][64];
    __shared__ float ps[32][256];
    const float* xrow = XN + (size_t)b * DROW;
    for (int i = tid; i < 2048; i += 256) xs[i >> 6][i & 63] = xrow[i];
    __syncthreads();

    float a[32], g[32];
    #pragma unroll
    for (int r = 0; r < 32; ++r) { a[r] = 0.f; g[r] = 0.f; }
    for (int k = 0; k < 64; ++k) {
        float wa = ldin(w1, ow1 + k * 512 + tid, bf);
        float wg = ldin(w1, ow1 + k * 512 + 256 + tid, bf);
        #pragma unroll
        for (int r = 0; r < 32; ++r) { float xv = xs[r][k]; a[r] += xv * wa; g[r] += xv * wg; }
    }
    float ba = ldin(b1, ob1 + tid, bf), bg = ldin(b1, ob1 + 256 + tid, bf);
    #pragma unroll
    for (int r = 0; r < 32; ++r)
        ps[r][tid] = (a[r] + ba) * gelu_exact(g[r] + bg);
    __syncthreads();

    for (int e = tid; e < 2048; e += 256) {
        int r = e >> 6, c = e & 63;
        float acc = 0.f;
        for (int j = 0; j < 256; ++j) acc += ps[r][j] * ldin(w2, ow2 + j * 64 + c, bf);
        acc += ldin(b2, ob2 + c, bf) + xs[r][c];
        X[(size_t)b * DROW + e] = acc;
    }
}

// ---------------- cast fp32 -> bf16 (flat, workspace) ----------------
__global__ __launch_bounds__(256) void k_cast_f2b(const float* __restrict__ in,
                                                  bf16* __restrict__ out) {
    int i = (blockIdx.x * 256 + threadIdx.x) * 4;
    #pragma unroll
    for (int j = 0; j < 4; ++j) out[i + j] = __float2bfloat16(in[i + j]);
}

// ---------------- transpose+cast external weight: in (RxC fp32/bf16, ld=C) -> out bf16 (CxR) ----------------
__global__ __launch_bounds__(256) void k_castT(const void* __restrict__ in, size_t eoff,
                                               int R, int C,
                                               bf16* __restrict__ out,
                                               const int* __restrict__ flag) {
    const int bf = *flag;
    __shared__ bf16 tile[32][33];
    const int tx = threadIdx.x & 31, ty = threadIdx.x >> 5;
    const int bx = blockIdx.x, by = blockIdx.y;   // bx: R-tiles, by: C-tiles
    #pragma unroll
    for (int k = 0; k < 4; ++k) {
        int r = bx * 32 + ty + k * 8;
        int c = by * 32 + tx;
        tile[ty + k * 8][tx] = __float2bfloat16(ldin(in, eoff + (size_t)r * C + c, bf));
    }
    __syncthreads();
    #pragma unroll
    for (int k = 0; k < 4; ++k) {
        int oc = by * 32 + ty + k * 8;   // output row (C dim)
        int orr = bx * 32 + tx;          // output col (R dim)
        out[(size_t)oc * R + orr] = tile[tx][ty + k * 8];
    }
}

// ---------------- transpose bf16 (strided input) ----------------
__global__ __launch_bounds__(256) void k_transpose_bf(const bf16* __restrict__ in, int ld,
                                                      int R, int C,
                                                      bf16* __restrict__ out) {
    __shared__ bf16 tile[32][33];
    const int tx = threadIdx.x & 31, ty = threadIdx.x >> 5;
    const int bx = blockIdx.x, by = blockIdx.y;
    #pragma unroll
    for (int k = 0; k < 4; ++k) {
        int r = bx * 32 + ty + k * 8;
        int c = by * 32 + tx;
        tile[ty + k * 8][tx] = in[(size_t)r * ld + c];
    }
    __syncthreads();
    #pragma unroll
    for (int k = 0; k < 4; ++k) {
        int oc = by * 32 + ty + k * 8;
        int orr = bx * 32 + tx;
        out[(size_t)oc * R + orr] = tile[tx][ty + k * 8];
    }
}

// ---------------- MFMA GEMM: C = alpha * A @ Bt^T (+bias)(+addend) ----------------
// A bf16 [M x K] row-major (lda); Bt bf16 [N x K] row-major (ldb); batched via z.
// Tile (WM*64) x (WN*64), 4 waves, each wave 64x64 via 16 mfma_f32_16x16x32_bf16.
// A-frag: lane holds A[m=lane&15][k=(lane>>4)*8+j]; B-frag: Bt[n=lane&15][k=...];
// D: row=(lane>>4)*4+r, col=lane&15  [guide §3, m89-verified].
template <int WM, int WN, bool OBF>
__global__ __launch_bounds__(256) void k_mfma(
    int M, int N, int K,
    const bf16* __restrict__ A, int lda, long long sA,
    const bf16* __restrict__ Bt, int ldb, long long sB,
    void* __restrict__ C, int ldc, long long sC,
    float alpha,
    const void* __restrict__ bias, size_t biasOff,
    const float* __restrict__ addend, int ldadd,
    const int* __restrict__ flag)
{
    constexpr int TM = WM * 64, TN = WN * 64;
    const int z = blockIdx.z;
    A  += (size_t)z * sA;
    Bt += (size_t)z * sB;
    const int m0 = blockIdx.y * TM, n0 = blockIdx.x * TN;
    const int tid = threadIdx.x, lane = tid & 63, wave = tid >> 6;
    const int wy = wave / WN, wx = wave % WN;
    __shared__ short As[TM][72];
    __shared__ short Bs[TN][72];
    f32x4 acc[4][4] = {};
    const int row8 = tid >> 3, chunk = (tid & 7) * 8;
    for (int k0 = 0; k0 < K; k0 += 64) {
        #pragma unroll
        for (int i = 0; i < TM / 32; ++i) {
            int r = i * 32 + row8;
            *(short8*)&As[r][chunk] =
                *(const short8*)(A + (size_t)(m0 + r) * lda + k0 + chunk);
        }
        #pragma unroll
        for (int i = 0; i < TN / 32; ++i) {
            int r = i * 32 + row8;
            *(short8*)&Bs[r][chunk] =
                *(const short8*)(Bt + (size_t)(n0 + r) * ldb + k0 + chunk);
        }
        __syncthreads();
        #pragma unroll
        for (int ks = 0; ks < 64; ks += 32) {
            short8 af[4], bfr[4];
            #pragma unroll
            for (int mt = 0; mt < 4; ++mt)
                af[mt] = *(const short8*)&As[wy * 64 + mt * 16 + (lane & 15)][ks + (lane >> 4) * 8];
            #pragma unroll
            for (int nt = 0; nt < 4; ++nt)
                bfr[nt] = *(const short8*)&Bs[wx * 64 + nt * 16 + (lane & 15)][ks + (lane >> 4) * 8];
            #pragma unroll
            for (int mt = 0; mt < 4; ++mt)
                #pragma unroll
                for (int nt = 0; nt < 4; ++nt)
                    acc[mt][nt] = __builtin_amdgcn_mfma_f32_16x16x32_bf16(
                        af[mt], bfr[nt], acc[mt][nt], 0, 0, 0);
        }
        __syncthreads();
    }
    const int bfl = bias ? *flag : 0;
    #pragma unroll
    for (int mt = 0; mt < 4; ++mt) {
        #pragma unroll
        for (int r = 0; r < 4; ++r) {
            int m = m0 + wy * 64 + mt * 16 + (lane >> 4) * 4 + r;
            #pragma unroll
            for (int nt = 0; nt < 4; ++nt) {
                int n = n0 + wx * 64 + nt * 16 + (lane & 15);
                float v = acc[mt][nt][r] * alpha;
                if (bias)   v += ldin(bias, biasOff + n, bfl);
                if (addend) v += addend[(size_t)m * ldadd + n];
                size_t idx = (size_t)z * sC + (size_t)m * ldc + n;
                if constexpr (OBF) ((bf16*)C)[idx] = __float2bfloat16(v);
                else               ((float*)C)[idx] = v;
            }
        }
    }
}

// ---------------- softmax rows of 2048: S fp32 -> P bf16 ----------------
__global__ __launch_bounds__(256) void k_softmax_bf(const float* __restrict__ S,
                                                    bf16* __restrict__ P) {
    const int row = blockIdx.x, tid = threadIdx.x;
    const float* r = S + (size_t)row * 2048;
    bf16* o = P + (size_t)row * 2048;
    __shared__ float red[4];
    float v[8];
    float mx = -1e30f;
    #pragma unroll
    for (int i = 0; i < 8; ++i) { v[i] = r[tid + i * 256]; mx = fmaxf(mx, v[i]); }
    #pragma unroll
    for (int off = 32; off; off >>= 1) mx = fmaxf(mx, __shfl_xor(mx, off));
    if ((tid & 63) == 0) red[tid >> 6] = mx;
    __syncthreads();
    mx = fmaxf(fmaxf(red[0], red[1]), fmaxf(red[2], red[3]));
    __syncthreads();
    float s = 0.f;
    #pragma unroll
    for (int i = 0; i < 8; ++i) { v[i] = __expf(v[i] - mx); s += v[i]; }
    #pragma unroll
    for (int off = 32; off; off >>= 1) s += __shfl_xor(s, off);
    if ((tid & 63) == 0) red[tid >> 6] = s;
    __syncthreads();
    float inv = 1.0f / (red[0] + red[1] + red[2] + red[3]);
    #pragma unroll
    for (int i = 0; i < 8; ++i) o[tid + i * 256] = __float2bfloat16(v[i] * inv);
}

// ---------------- GEGLU: H fp32 [2048x2048] -> Pm bf16 [2048x1024] ----------------
__global__ __launch_bounds__(256) void k_geglu(const float* __restrict__ H,
                                               bf16* __restrict__ P) {
    int i = blockIdx.x * 256 + threadIdx.x;
    int r = i >> 10, j = i & 1023;
    float a = H[(size_t)r * 2048 + j];
    float g = H[(size_t)r * 2048 + 1024 + j];
    P[i] = __float2bfloat16(a * gelu_exact(g));
}

// ---------------- final cast fp32 -> output dtype ----------------
__global__ __launch_bounds__(256) void k_cast_out(const float* __restrict__ X,
                                                  void* __restrict__ out,
                                                  const int* __restrict__ flag) {
    const int bf = *flag;
    int i = blockIdx.x * 256 + threadIdx.x;
    if (bf) ((bf16*)out)[i] = __float2bfloat16(X[i]);
    else    ((float*)out)[i] = X[i];
}

// =====================================================================
extern "C" void kernel_launch(void* const* d_in, const int* in_sizes, int n_in,
                              void* d_out, int out_size, void* d_ws, size_t ws_size,
                              hipStream_t stream) {
    const void* x       = d_in[0];
    const void* x_cont  = d_in[1];
    const void* c_ln1_g = d_in[2];
    const void* c_ln1_b = d_in[3];
    const void* c_wqkv  = d_in[4];
    const void* c_wo_w  = d_in[5];
    const void* c_wo_b  = d_in[6];
    const void* c_ln2_g = d_in[7];
    const void* c_ln2_b = d_in[8];
    const void* c_w1    = d_in[9];
    const void* c_b1    = d_in[10];
    const void* c_w2    = d_in[11];
    const void* c_b2    = d_in[12];
    const void* r_ln1_g = d_in[13];
    const void* r_ln1_b = d_in[14];
    const void* r_wqkv  = d_in[15];
    const void* r_wo_w  = d_in[16];
    const void* r_wo_b  = d_in[17];
    const void* r_ln2_g = d_in[18];
    const void* r_ln2_b = d_in[19];
    const void* r_w1    = d_in[20];
    const void* r_b1    = d_in[21];
    const void* r_w2    = d_in[22];
    const void* r_b2    = d_in[23];

    const size_t NX = (size_t)BD * NF * DIMC;        // 4,194,304
    float* X   = (float*)d_ws;
    float* XN  = X   + NX;
    float* ACC = XN  + NX;
    float* H   = ACC + NX;                            // 2048x2048 fp32
    bf16* XNh  = (bf16*)(H + NX);                     // 4,194,304 bf16
    bf16* QKVh = XNh + NX;                            // 2048x1536 bf16
    bf16* Vt   = QKVh + (size_t)2048 * 1536;          // 512x2048 bf16
    bf16* Oh   = Vt + (size_t)512 * 2048;             // 2048x512 bf16
    bf16* Wt   = Oh + (size_t)2048 * 512;             // up to 2048x2048 bf16
    bf16* Pm   = Wt + (size_t)2048 * 2048;            // 2048x1024 bf16
    bf16* Ph2  = Pm + (size_t)2048 * 1024;            // 2x2048x2048 bf16
    float* S2  = (float*)(Ph2 + (size_t)2 * 2048 * 2048);  // 2x2048x2048 fp32
    float* END = S2 + (size_t)2 * 2048 * 2048;
    int*  flag = (int*)END;
    const size_t need = ((size_t)((char*)END - (char*)d_ws)) + 64;
    if (ws_size < need) return;

    const long long SH = (long long)2048 * 2048;      // per-head S/P stride

    k_detect<<<1, 64, 0, stream>>>(x, flag);
    k_concat<<<16384, 256, 0, stream>>>(x, x_cont, X, flag);

    for (int d = 0; d < 4; ++d) {
        // ---- col block (unchanged) ----
        k_ln64<<<16384, 256, 0, stream>>>(X, XN, c_ln1_g, c_ln1_b, (size_t)d * 64, flag);
        k_bias_init<<<16384, 256, 0, stream>>>(XN, c_wo_b, ACC, (size_t)d * 64, flag);
        k_col_attn<<<dim3(BD, HEADS), 256, 0, stream>>>(
            XN, c_wqkv, c_wo_w, ACC,
            (size_t)d * 64 * 1536, (size_t)d * 512 * 64, flag);
        k_ln64<<<16384, 256, 0, stream>>>(ACC, XN, c_ln2_g, c_ln2_b, (size_t)d * 64, flag);
        k_col_mlp<<<BD, 256, 0, stream>>>(
            XN, c_w1, c_b1, c_w2, c_b2, X,
            (size_t)d * 64 * 512, (size_t)d * 512,
            (size_t)d * 256 * 64, (size_t)d * 64, flag);

        // ---- row block (MFMA) ----
        k_ln_row<<<BD, 256, 0, stream>>>(X, XN, r_ln1_g, r_ln1_b, (size_t)d * DROW, flag);
        k_cast_f2b<<<4096, 256, 0, stream>>>(XN, XNh);
        // QKVh = XNh @ r_wqkv (bf16 out)
        k_castT<<<dim3(64, 48), 256, 0, stream>>>(r_wqkv, (size_t)d * 2048 * 1536, 2048, 1536, Wt, flag);
        k_mfma<2, 2, true><<<dim3(12, 16, 1), 256, 0, stream>>>(
            2048, 1536, 2048, XNh, 2048, 0, Wt, 2048, 0,
            QKVh, 1536, 0, 1.0f, nullptr, 0, nullptr, 0, flag);
        // Vt = V^T (512x2048)
        k_transpose_bf<<<dim3(64, 16), 256, 0, stream>>>(QKVh + 1024, 1536, 2048, 512, Vt);
        // attention, 4 head-pairs
        for (int hp = 0; hp < 4; ++hp) {
            const int h0 = 2 * hp;
            k_mfma<2, 2, false><<<dim3(16, 16, 2), 256, 0, stream>>>(
                2048, 2048, 64,
                QKVh + h0 * 64, 1536, 64,
                QKVh + 512 + h0 * 64, 1536, 64,
                S2, 2048, SH, 0.125f, nullptr, 0, nullptr, 0, flag);
            k_softmax_bf<<<4096, 256, 0, stream>>>(S2, Ph2);
            k_mfma<4, 1, true><<<dim3(1, 8, 2), 256, 0, stream>>>(
                2048, 64, 2048,
                Ph2, 2048, SH,
                Vt + (size_t)h0 * 64 * 2048, 2048, (long long)64 * 2048,
                Oh + h0 * 64, 512, 64, 1.0f, nullptr, 0, nullptr, 0, flag);
        }
        // ACC = Oh @ r_wo_w + r_wo_b + XN
        k_castT<<<dim3(16, 64), 256, 0, stream>>>(r_wo_w, (size_t)d * 512 * 2048, 512, 2048, Wt, flag);
        k_mfma<2, 2, false><<<dim3(16, 16, 1), 256, 0, stream>>>(
            2048, 2048, 512, Oh, 512, 0, Wt, 512, 0,
            ACC, 2048, 0, 1.0f, r_wo_b, (size_t)d * DROW, XN, 2048, flag);
        k_ln_row<<<BD, 256, 0, stream>>>(ACC, XN, r_ln2_g, r_ln2_b, (size_t)d * DROW, flag);
        k_cast_f2b<<<4096, 256, 0, stream>>>(XN, XNh);
        // H = XNh @ r_w1 + r_b1 (fp32 out)
        k_castT<<<dim3(64, 64), 256, 0, stream>>>(r_w1, (size_t)d * 2048 * 2048, 2048, 2048, Wt, flag);
        k_mfma<2, 2, false><<<dim3(16, 16, 1), 256, 0, stream>>>(
            2048, 2048, 2048, XNh, 2048, 0, Wt, 2048, 0,
            H, 2048, 0, 1.0f, r_b1, (size_t)d * 2048, nullptr, 0, flag);
        k_geglu<<<8192, 256, 0, stream>>>(H, Pm);
        // X = Pm @ r_w2 + r_b2 + XN
        k_castT<<<dim3(32, 64), 256, 0, stream>>>(r_w2, (size_t)d * 1024 * 2048, 1024, 2048, Wt, flag);
        k_mfma<2, 2, false><<<dim3(16, 16, 1), 256, 0, stream>>>(
            2048, 2048, 1024, Pm, 1024, 0, Wt, 1024, 0,
            X, 2048, 0, 1.0f, r_b2, (size_t)d * DROW, XN, 2048, flag);
    }

    k_cast_out<<<16384, 256, 0, stream>>>(X, d_out, flag);
}

// Round 5
// 3419.228 us; speedup vs baseline: 3.4615x; 1.9586x over previous
//
#include <hip/hip_runtime.h>
#include <hip/hip_bf16.h>
#include <cstddef>

#define BD    2048
#define NF    32
#define DIMC  64
#define HEADS 8
#define DROW  2048
#define LNEPS 1e-5f

typedef __hip_bfloat16 bf16;
typedef __attribute__((ext_vector_type(8))) short short8;
typedef __attribute__((ext_vector_type(4))) float f32x4;

// dtype-flagged external-input load: flag=1 -> bf16, flag=0 -> fp32
__device__ inline float ldin(const void* p, size_t i, int bf) {
    if (bf) return __bfloat162float(((const bf16*)p)[i]);
    return ((const float*)p)[i];
}

__device__ inline float gelu_exact(float x) {
    return 0.5f * x * (1.0f + erff(x * 0.70710678118654752f));
}

// ---------------- dtype detector (external inputs fp32 vs bf16) ----------------
__global__ __launch_bounds__(64) void k_detect(const void* __restrict__ x,
                                               int* __restrict__ flag) {
    int i = threadIdx.x;
    size_t idx = (size_t)(2 * i) * 16384;
    unsigned short u = ((const unsigned short*)x)[idx];
    int e = (u >> 7) & 0xFF;
    int plausible = (e == 0) || (e >= 96 && e <= 132);
    unsigned long long m = __ballot(plausible);
    if (i == 0) *flag = (__popcll(m) >= 48) ? 1 : 0;
}

// ---------------- concat [x, x_cont] -> X (fp32) ----------------
__global__ __launch_bounds__(256) void k_concat(const void* __restrict__ x,
                                                const void* __restrict__ xc,
                                                float* __restrict__ X,
                                                const int* __restrict__ flag) {
    const int bf = *flag;
    int i = blockIdx.x * 256 + threadIdx.x;
    int d = i & 63;
    int f = (i >> 6) & 31;
    int b = i >> 11;
    float v = (f < 16) ? ldin(x,  ((size_t)b * 16 + f) * 64 + d, bf)
                       : ldin(xc, ((size_t)b * 16 + (f - 16)) * 64 + d, bf);
    X[i] = v;
}

// ---------------- LayerNorm over last-64 ----------------
__global__ __launch_bounds__(256) void k_ln64(const float* __restrict__ in,
                                              float* __restrict__ out,
                                              const void* __restrict__ g,
                                              const void* __restrict__ b,
                                              size_t eoff,
                                              const int* __restrict__ flag) {
    const int bf = *flag;
    int row  = blockIdx.x * 4 + (threadIdx.x >> 6);
    int lane = threadIdx.x & 63;
    float v = in[(size_t)row * 64 + lane];
    float s = v;
    #pragma unroll
    for (int off = 32; off; off >>= 1) s += __shfl_xor(s, off);
    float mean = s * (1.0f / 64.0f);
    float dx = v - mean;
    float s2 = dx * dx;
    #pragma unroll
    for (int off = 32; off; off >>= 1) s2 += __shfl_xor(s2, off);
    float inv = rsqrtf(s2 * (1.0f / 64.0f) + LNEPS);
    out[(size_t)row * 64 + lane] =
        dx * inv * ldin(g, eoff + lane, bf) + ldin(b, eoff + lane, bf);
}

// ---------------- LayerNorm over 2048 ----------------
__global__ __launch_bounds__(256) void k_ln_row(const float* __restrict__ in,
                                                float* __restrict__ out,
                                                const void* __restrict__ g,
                                                const void* __restrict__ b,
                                                size_t eoff,
                                                const int* __restrict__ flag) {
    const int bf = *flag;
    const int row = blockIdx.x, tid = threadIdx.x;
    __shared__ float red[4];
    const float* r = in + (size_t)row * DROW;
    float v[8];
    float s = 0.f;
    #pragma unroll
    for (int i = 0; i < 8; ++i) { v[i] = r[tid + i * 256]; s += v[i]; }
    #pragma unroll
    for (int off = 32; off; off >>= 1) s += __shfl_xor(s, off);
    if ((tid & 63) == 0) red[tid >> 6] = s;
    __syncthreads();
    float mean = (red[0] + red[1] + red[2] + red[3]) * (1.0f / DROW);
    __syncthreads();
    float s2 = 0.f;
    #pragma unroll
    for (int i = 0; i < 8; ++i) { float dx = v[i] - mean; s2 += dx * dx; }
    #pragma unroll
    for (int off = 32; off; off >>= 1) s2 += __shfl_xor(s2, off);
    if ((tid & 63) == 0) red[tid >> 6] = s2;
    __syncthreads();
    float inv = rsqrtf((red[0] + red[1] + red[2] + red[3]) * (1.0f / DROW) + LNEPS);
    #pragma unroll
    for (int i = 0; i < 8; ++i) {
        int j = tid + i * 256;
        out[(size_t)row * DROW + j] =
            (v[i] - mean) * inv * ldin(g, eoff + j, bf) + ldin(b, eoff + j, bf);
    }
}

// ---------------- cast fp32 -> bf16 (flat) ----------------
__global__ __launch_bounds__(256) void k_cast_f2b(const float* __restrict__ in,
                                                  bf16* __restrict__ out) {
    int i = (blockIdx.x * 256 + threadIdx.x) * 4;
    #pragma unroll
    for (int j = 0; j < 4; ++j) out[i + j] = __float2bfloat16(in[i + j]);
}

// ---------------- transpose+cast external weight: in (RxC, ld=C) -> out bf16 (CxR) ----------------
__global__ __launch_bounds__(256) void k_castT(const void* __restrict__ in, size_t eoff,
                                               int R, int C,
                                               bf16* __restrict__ out,
                                               const int* __restrict__ flag) {
    const int bf = *flag;
    __shared__ bf16 tile[32][33];
    const int tx = threadIdx.x & 31, ty = threadIdx.x >> 5;
    const int bx = blockIdx.x, by = blockIdx.y;
    #pragma unroll
    for (int k = 0; k < 4; ++k) {
        int r = bx * 32 + ty + k * 8;
        int c = by * 32 + tx;
        tile[ty + k * 8][tx] = __float2bfloat16(ldin(in, eoff + (size_t)r * C + c, bf));
    }
    __syncthreads();
    #pragma unroll
    for (int k = 0; k < 4; ++k) {
        int oc = by * 32 + ty + k * 8;
        int orr = bx * 32 + tx;
        out[(size_t)oc * R + orr] = tile[tx][ty + k * 8];
    }
}

// ---------------- transpose bf16 (strided input) ----------------
__global__ __launch_bounds__(256) void k_transpose_bf(const bf16* __restrict__ in, int ld,
                                                      int R, int C,
                                                      bf16* __restrict__ out) {
    __shared__ bf16 tile[32][33];
    const int tx = threadIdx.x & 31, ty = threadIdx.x >> 5;
    const int bx = blockIdx.x, by = blockIdx.y;
    #pragma unroll
    for (int k = 0; k < 4; ++k) {
        int r = bx * 32 + ty + k * 8;
        int c = by * 32 + tx;
        tile[ty + k * 8][tx] = in[(size_t)r * ld + c];
    }
    __syncthreads();
    #pragma unroll
    for (int k = 0; k < 4; ++k) {
        int oc = by * 32 + ty + k * 8;
        int orr = bx * 32 + tx;
        out[(size_t)oc * R + orr] = tile[tx][ty + k * 8];
    }
}

// ---------------- MFMA GEMM: C = alpha * A @ Bt^T (+bias)(+addend) ----------------
// A bf16 [M x K] row-major (lda); Bt bf16 [N x K] row-major (ldb); batched via z.
// 4 waves, wave = 64x64 via 16 mfma_f32_16x16x32_bf16. Layouts m89-verified.
template <int WM, int WN, bool OBF>
__global__ __launch_bounds__(256) void k_mfma(
    int M, int N, int K,
    const bf16* __restrict__ A, int lda, long long sA,
    const bf16* __restrict__ Bt, int ldb, long long sB,
    void* __restrict__ C, int ldc, long long sC,
    float alpha,
    const void* __restrict__ bias, size_t biasOff,
    const float* __restrict__ addend, int ldadd,
    const int* __restrict__ flag)
{
    constexpr int TM = WM * 64, TN = WN * 64;
    const int z = blockIdx.z;
    A  += (size_t)z * sA;
    Bt += (size_t)z * sB;
    const int m0 = blockIdx.y * TM, n0 = blockIdx.x * TN;
    const int tid = threadIdx.x, lane = tid & 63, wave = tid >> 6;
    const int wy = wave / WN, wx = wave % WN;
    __shared__ short As[TM][72];
    __shared__ short Bs[TN][72];
    f32x4 acc[4][4] = {};
    const int row8 = tid >> 3, chunk = (tid & 7) * 8;
    for (int k0 = 0; k0 < K; k0 += 64) {
        #pragma unroll
        for (int i = 0; i < TM / 32; ++i) {
            int r = i * 32 + row8;
            *(short8*)&As[r][chunk] =
                *(const short8*)(A + (size_t)(m0 + r) * lda + k0 + chunk);
        }
        #pragma unroll
        for (int i = 0; i < TN / 32; ++i) {
            int r = i * 32 + row8;
            *(short8*)&Bs[r][chunk] =
                *(const short8*)(Bt + (size_t)(n0 + r) * ldb + k0 + chunk);
        }
        __syncthreads();
        #pragma unroll
        for (int ks = 0; ks < 64; ks += 32) {
            short8 af[4], bfr[4];
            #pragma unroll
            for (int mt = 0; mt < 4; ++mt)
                af[mt] = *(const short8*)&As[wy * 64 + mt * 16 + (lane & 15)][ks + (lane >> 4) * 8];
            #pragma unroll
            for (int nt = 0; nt < 4; ++nt)
                bfr[nt] = *(const short8*)&Bs[wx * 64 + nt * 16 + (lane & 15)][ks + (lane >> 4) * 8];
            #pragma unroll
            for (int mt = 0; mt < 4; ++mt)
                #pragma unroll
                for (int nt = 0; nt < 4; ++nt)
                    acc[mt][nt] = __builtin_amdgcn_mfma_f32_16x16x32_bf16(
                        af[mt], bfr[nt], acc[mt][nt], 0, 0, 0);
        }
        __syncthreads();
    }
    const int bfl = bias ? *flag : 0;
    #pragma unroll
    for (int mt = 0; mt < 4; ++mt) {
        #pragma unroll
        for (int r = 0; r < 4; ++r) {
            int m = m0 + wy * 64 + mt * 16 + (lane >> 4) * 4 + r;
            #pragma unroll
            for (int nt = 0; nt < 4; ++nt) {
                int n = n0 + wx * 64 + nt * 16 + (lane & 15);
                float v = acc[mt][nt][r] * alpha;
                if (bias)   v += ldin(bias, biasOff + n, bfl);
                if (addend) v += addend[(size_t)m * ldadd + n];
                size_t idx = (size_t)z * sC + (size_t)m * ldc + n;
                if constexpr (OBF) ((bf16*)C)[idx] = __float2bfloat16(v);
                else               ((float*)C)[idx] = v;
            }
        }
    }
}

// ---------------- fused MFMA col attention: one wave per (sample, head) ----------------
// QKVc: [NS*32 x 1536] bf16 (chunk-local samples); Oh: [NS*32 x 512] bf16
__global__ __launch_bounds__(256) void k_col_attn_mfma(
    const bf16* __restrict__ QKVc, bf16* __restrict__ Oh)
{
    __shared__ __align__(16) short pbuf[4][32][40];
    __shared__ __align__(16) short vbuf[4][32][72];
    const int tid = threadIdx.x, lane = tid & 63, wave = tid >> 6;
    const int task = blockIdx.x * 4 + wave;       // sample*8 + head
    const int s = task >> 3, h = task & 7;
    const int l15 = lane & 15, quad = lane >> 4;
    const bf16* qkv = QKVc + (size_t)s * 32 * 1536;

    // Q/K fragments straight from global (A/B-operand layout)
    short8 qf[2][2], kf[2][2];
    #pragma unroll
    for (int t = 0; t < 2; ++t)
        #pragma unroll
        for (int kc = 0; kc < 2; ++kc) {
            qf[t][kc] = *(const short8*)(qkv + (size_t)(t * 16 + l15) * 1536 + h * 64 + kc * 32 + quad * 8);
            kf[t][kc] = *(const short8*)(qkv + (size_t)(t * 16 + l15) * 1536 + 512 + h * 64 + kc * 32 + quad * 8);
        }
    f32x4 S[2][2] = {};
    #pragma unroll
    for (int mt = 0; mt < 2; ++mt)
        #pragma unroll
        for (int nt = 0; nt < 2; ++nt)
            #pragma unroll
            for (int kc = 0; kc < 2; ++kc)
                S[mt][nt] = __builtin_amdgcn_mfma_f32_16x16x32_bf16(
                    qf[mt][kc], kf[nt][kc], S[mt][nt], 0, 0, 0);

    // stage V [32 feats x 64 dims] into LDS (coalesced 16B rows)
    #pragma unroll
    for (int it = 0; it < 4; ++it) {
        int k = it * 8 + (lane >> 3);
        *(short8*)&vbuf[wave][k][(lane & 7) * 8] =
            *(const short8*)(qkv + (size_t)k * 1536 + 1024 + h * 64 + (lane & 7) * 8);
    }

    // softmax per row (row = mt*16 + quad*4 + ri; cols spread over l15 x 2 ntiles)
    #pragma unroll
    for (int mt = 0; mt < 2; ++mt) {
        #pragma unroll
        for (int ri = 0; ri < 4; ++ri) {
            float l0 = S[mt][0][ri] * 0.125f, l1 = S[mt][1][ri] * 0.125f;
            float m = fmaxf(l0, l1);
            #pragma unroll
            for (int msk = 1; msk < 16; msk <<= 1) m = fmaxf(m, __shfl_xor(m, msk));
            float e0 = __expf(l0 - m), e1 = __expf(l1 - m);
            float sum = e0 + e1;
            #pragma unroll
            for (int msk = 1; msk < 16; msk <<= 1) sum += __shfl_xor(sum, msk);
            float inv = 1.0f / sum;
            int row = mt * 16 + quad * 4 + ri;
            *(bf16*)&pbuf[wave][row][l15]      = __float2bfloat16(e0 * inv);
            *(bf16*)&pbuf[wave][row][16 + l15] = __float2bfloat16(e1 * inv);
        }
    }
    __syncthreads();   // LDS writes (P, V) visible before cross-lane reads

    // P as A-operand (K=32), V^T as B-operand
    short8 pa[2];
    #pragma unroll
    for (int mt = 0; mt < 2; ++mt)
        pa[mt] = *(const short8*)&pbuf[wave][mt * 16 + l15][quad * 8];
    f32x4 O[2][4] = {};
    #pragma unroll
    for (int nt = 0; nt < 4; ++nt) {
        short8 vb;
        #pragma unroll
        for (int j = 0; j < 8; ++j) vb[j] = vbuf[wave][quad * 8 + j][nt * 16 + l15];
        #pragma unroll
        for (int mt = 0; mt < 2; ++mt)
            O[mt][nt] = __builtin_amdgcn_mfma_f32_16x16x32_bf16(pa[mt], vb, O[mt][nt], 0, 0, 0);
    }
    #pragma unroll
    for (int mt = 0; mt < 2; ++mt)
        #pragma unroll
        for (int nt = 0; nt < 4; ++nt)
            #pragma unroll
            for (int ri = 0; ri < 4; ++ri) {
                size_t row = (size_t)s * 32 + mt * 16 + quad * 4 + ri;
                Oh[row * 512 + h * 64 + nt * 16 + l15] = __float2bfloat16(O[mt][nt][ri]);
            }
}

// ---------------- softmax rows of 2048: S fp32 -> P bf16 (row attention) ----------------
__global__ __launch_bounds__(256) void k_softmax_bf(const float* __restrict__ S,
                                                    bf16* __restrict__ P) {
    const int row = blockIdx.x, tid = threadIdx.x;
    const float* r = S + (size_t)row * 2048;
    bf16* o = P + (size_t)row * 2048;
    __shared__ float red[4];
    float v[8];
    float mx = -1e30f;
    #pragma unroll
    for (int i = 0; i < 8; ++i) { v[i] = r[tid + i * 256]; mx = fmaxf(mx, v[i]); }
    #pragma unroll
    for (int off = 32; off; off >>= 1) mx = fmaxf(mx, __shfl_xor(mx, off));
    if ((tid & 63) == 0) red[tid >> 6] = mx;
    __syncthreads();
    mx = fmaxf(fmaxf(red[0], red[1]), fmaxf(red[2], red[3]));
    __syncthreads();
    float s = 0.f;
    #pragma unroll
    for (int i = 0; i < 8; ++i) { v[i] = __expf(v[i] - mx); s += v[i]; }
    #pragma unroll
    for (int off = 32; off; off >>= 1) s += __shfl_xor(s, off);
    if ((tid & 63) == 0) red[tid >> 6] = s;
    __syncthreads();
    float inv = 1.0f / (red[0] + red[1] + red[2] + red[3]);
    #pragma unroll
    for (int i = 0; i < 8; ++i) o[tid + i * 256] = __float2bfloat16(v[i] * inv);
}

// ---------------- GEGLU row: H fp32 [2048x2048] -> Pm bf16 [2048x1024] ----------------
__global__ __launch_bounds__(256) void k_geglu_row(const float* __restrict__ H,
                                                   bf16* __restrict__ P) {
    int i = blockIdx.x * 256 + threadIdx.x;
    int r = i >> 10, j = i & 1023;
    float a = H[(size_t)r * 2048 + j];
    float g = H[(size_t)r * 2048 + 1024 + j];
    P[i] = __float2bfloat16(a * gelu_exact(g));
}

// ---------------- GEGLU col: H1 bf16 [65536x512] -> Pc bf16 [65536x256] ----------------
__global__ __launch_bounds__(256) void k_geglu_col(const bf16* __restrict__ H,
                                                   bf16* __restrict__ P) {
    int i = blockIdx.x * 256 + threadIdx.x;
    int r = i >> 8, j = i & 255;
    float a = __bfloat162float(H[(size_t)r * 512 + j]);
    float g = __bfloat162float(H[(size_t)r * 512 + 256 + j]);
    P[i] = __float2bfloat16(a * gelu_exact(g));
}

// ---------------- final cast fp32 -> output dtype ----------------
__global__ __launch_bounds__(256) void k_cast_out(const float* __restrict__ X,
                                                  void* __restrict__ out,
                                                  const int* __restrict__ flag) {
    const int bf = *flag;
    int i = blockIdx.x * 256 + threadIdx.x;
    if (bf) ((bf16*)out)[i] = __float2bfloat16(X[i]);
    else    ((float*)out)[i] = X[i];
}

// =====================================================================
extern "C" void kernel_launch(void* const* d_in, const int* in_sizes, int n_in,
                              void* d_out, int out_size, void* d_ws, size_t ws_size,
                              hipStream_t stream) {
    const void* x       = d_in[0];
    const void* x_cont  = d_in[1];
    const void* c_ln1_g = d_in[2];
    const void* c_ln1_b = d_in[3];
    const void* c_wqkv  = d_in[4];
    const void* c_wo_w  = d_in[5];
    const void* c_wo_b  = d_in[6];
    const void* c_ln2_g = d_in[7];
    const void* c_ln2_b = d_in[8];
    const void* c_w1    = d_in[9];
    const void* c_b1    = d_in[10];
    const void* c_w2    = d_in[11];
    const void* c_b2    = d_in[12];
    const void* r_ln1_g = d_in[13];
    const void* r_ln1_b = d_in[14];
    const void* r_wqkv  = d_in[15];
    const void* r_wo_w  = d_in[16];
    const void* r_wo_b  = d_in[17];
    const void* r_ln2_g = d_in[18];
    const void* r_ln2_b = d_in[19];
    const void* r_w1    = d_in[20];
    const void* r_b1    = d_in[21];
    const void* r_w2    = d_in[22];
    const void* r_b2    = d_in[23];

    const size_t NX = (size_t)BD * NF * DIMC;        // 4,194,304 tokens*64
    float* X   = (float*)d_ws;
    float* XN  = X   + NX;
    float* ACC = XN  + NX;
    bf16* XNh  = (bf16*)(ACC + NX);                   // NX bf16
    bf16* WtR  = XNh + NX;                            // row weights (<=2048x2048)
    bf16* WcQ  = WtR + (size_t)2048 * 2048;           // 1536x64
    bf16* WcO  = WcQ + 98304;                         // 64x512
    bf16* Wc1  = WcO + 32768;                         // 512x64
    bf16* Wc2  = Wc1 + 32768;                         // 64x256
    bf16* Sc   = Wc2 + 16384;                         // scratch union base
    // col attn (chunked, NS=512 samples): QKVc + full Oh
    bf16* QKVc = Sc;                                  // 16384x1536 = 25,165,824
    bf16* OhC  = Sc + 25165824;                       // 65536x512  = 33,554,432
    // col MLP:
    bf16* H1   = Sc;                                  // 65536x512
    bf16* Pc   = Sc + 33554432;                       // 65536x256
    // row block:
    bf16* QKVhR = Sc;                                 // 2048x1536
    bf16* VtR   = QKVhR + 3145728;                    // 512x2048
    bf16* OhR   = VtR + 1048576;                      // 2048x512
    bf16* PmR   = OhR + 1048576;                      // 2048x1024
    bf16* Ph2   = PmR + 2097152;                      // 2x2048x2048
    float* S2   = (float*)(Ph2 + 8388608);            // 2x2048x2048 fp32
    float* Hrow = S2 + 8388608;                       // 2048x2048 fp32
    char* scEnd = (char*)Sc + 117440512;              // max(col attn) bytes
    int*  flag  = (int*)scEnd;
    const size_t need = (size_t)(scEnd + 64 - (char*)d_ws);
    if (ws_size < need) return;

    const long long SH = (long long)2048 * 2048;

    k_detect<<<1, 64, 0, stream>>>(x, flag);
    k_concat<<<16384, 256, 0, stream>>>(x, x_cont, X, flag);

    for (int d = 0; d < 4; ++d) {
        // ================= col block (MFMA) =================
        k_ln64<<<16384, 256, 0, stream>>>(X, XN, c_ln1_g, c_ln1_b, (size_t)d * 64, flag);
        k_cast_f2b<<<4096, 256, 0, stream>>>(XN, XNh);
        k_castT<<<dim3(2, 48), 256, 0, stream>>>(c_wqkv, (size_t)d * 64 * 1536, 64, 1536, WcQ, flag);
        for (int c = 0; c < 4; ++c) {
            // QKVc = XNh[chunk] @ c_wqkv   [16384 x 1536]
            k_mfma<2, 2, true><<<dim3(12, 128, 1), 256, 0, stream>>>(
                16384, 1536, 64, XNh + (size_t)c * 1048576, 64, 0,
                WcQ, 64, 0, QKVc, 1536, 0, 1.0f, nullptr, 0, nullptr, 0, flag);
            // fused attention: 512 samples x 8 heads, 1 wave each
            k_col_attn_mfma<<<1024, 256, 0, stream>>>(QKVc, OhC + (size_t)c * 8388608);
        }
        // ACC = OhC @ c_wo_w + c_wo_b + XN
        k_castT<<<dim3(16, 2), 256, 0, stream>>>(c_wo_w, (size_t)d * 512 * 64, 512, 64, WcO, flag);
        k_mfma<4, 1, false><<<dim3(1, 256, 1), 256, 0, stream>>>(
            65536, 64, 512, OhC, 512, 0, WcO, 512, 0,
            ACC, 64, 0, 1.0f, c_wo_b, (size_t)d * 64, XN, 64, flag);
        k_ln64<<<16384, 256, 0, stream>>>(ACC, XN, c_ln2_g, c_ln2_b, (size_t)d * 64, flag);
        k_cast_f2b<<<4096, 256, 0, stream>>>(XN, XNh);
        // H1 = XNh @ c_w1 + c_b1 (bf16)
        k_castT<<<dim3(2, 16), 256, 0, stream>>>(c_w1, (size_t)d * 64 * 512, 64, 512, Wc1, flag);
        k_mfma<2, 2, true><<<dim3(4, 512, 1), 256, 0, stream>>>(
            65536, 512, 64, XNh, 64, 0, Wc1, 64, 0,
            H1, 512, 0, 1.0f, c_b1, (size_t)d * 512, nullptr, 0, flag);
        k_geglu_col<<<65536, 256, 0, stream>>>(H1, Pc);
        // X = Pc @ c_w2 + c_b2 + XN
        k_castT<<<dim3(8, 2), 256, 0, stream>>>(c_w2, (size_t)d * 256 * 64, 256, 64, Wc2, flag);
        k_mfma<4, 1, false><<<dim3(1, 256, 1), 256, 0, stream>>>(
            65536, 64, 256, Pc, 256, 0, Wc2, 256, 0,
            X, 64, 0, 1.0f, c_b2, (size_t)d * 64, XN, 64, flag);

        // ================= row block (MFMA, as R4) =================
        k_ln_row<<<BD, 256, 0, stream>>>(X, XN, r_ln1_g, r_ln1_b, (size_t)d * DROW, flag);
        k_cast_f2b<<<4096, 256, 0, stream>>>(XN, XNh);
        k_castT<<<dim3(64, 48), 256, 0, stream>>>(r_wqkv, (size_t)d * 2048 * 1536, 2048, 1536, WtR, flag);
        k_mfma<2, 2, true><<<dim3(12, 16, 1), 256, 0, stream>>>(
            2048, 1536, 2048, XNh, 2048, 0, WtR, 2048, 0,
            QKVhR, 1536, 0, 1.0f, nullptr, 0, nullptr, 0, flag);
        k_transpose_bf<<<dim3(64, 16), 256, 0, stream>>>(QKVhR + 1024, 1536, 2048, 512, VtR);
        for (int hp = 0; hp < 4; ++hp) {
            const int h0 = 2 * hp;
            k_mfma<2, 2, false><<<dim3(16, 16, 2), 256, 0, stream>>>(
                2048, 2048, 64,
                QKVhR + h0 * 64, 1536, 64,
                QKVhR + 512 + h0 * 64, 1536, 64,
                S2, 2048, SH, 0.125f, nullptr, 0, nullptr, 0, flag);
            k_softmax_bf<<<4096, 256, 0, stream>>>(S2, Ph2);
            k_mfma<4, 1, true><<<dim3(1, 8, 2), 256, 0, stream>>>(
                2048, 64, 2048,
                Ph2, 2048, SH,
                VtR + (size_t)h0 * 64 * 2048, 2048, (long long)64 * 2048,
                OhR + h0 * 64, 512, 64, 1.0f, nullptr, 0, nullptr, 0, flag);
        }
        k_castT<<<dim3(16, 64), 256, 0, stream>>>(r_wo_w, (size_t)d * 512 * 2048, 512, 2048, WtR, flag);
        k_mfma<2, 2, false><<<dim3(16, 16, 1), 256, 0, stream>>>(
            2048, 2048, 512, OhR, 512, 0, WtR, 512, 0,
            ACC, 2048, 0, 1.0f, r_wo_b, (size_t)d * DROW, XN, 2048, flag);
        k_ln_row<<<BD, 256, 0, stream>>>(ACC, XN, r_ln2_g, r_ln2_b, (size_t)d * DROW, flag);
        k_cast_f2b<<<4096, 256, 0, stream>>>(XN, XNh);
        k_castT<<<dim3(64, 64), 256, 0, stream>>>(r_w1, (size_t)d * 2048 * 2048, 2048, 2048, WtR, flag);
        k_mfma<2, 2, false><<<dim3(16, 16, 1), 256, 0, stream>>>(
            2048, 2048, 2048, XNh, 2048, 0, WtR, 2048, 0,
            Hrow, 2048, 0, 1.0f, r_b1, (size_t)d * 2048, nullptr, 0, flag);
        k_geglu_row<<<8192, 256, 0, stream>>>(Hrow, PmR);
        k_castT<<<dim3(32, 64), 256, 0, stream>>>(r_w2, (size_t)d * 1024 * 2048, 1024, 2048, WtR, flag);
        k_mfma<2, 2, false><<<dim3(16, 16, 1), 256, 0, stream>>>(
            2048, 2048, 1024, PmR, 1024, 0, WtR, 1024, 0,
            X, 2048, 0, 1.0f, r_b2, (size_t)d * DROW, XN, 2048, flag);
    }

    k_cast_out<<<16384, 256, 0, stream>>>(X, d_out, flag);
}

// Round 6
// 2523.651 us; speedup vs baseline: 4.6899x; 1.3549x over previous
//
#include <hip/hip_runtime.h>
#include <hip/hip_bf16.h>
#include <cstddef>

#define BD    2048
#define NF    32
#define DIMC  64
#define HEADS 8
#define DROW  2048
#define LNEPS 1e-5f

typedef __hip_bfloat16 bf16;
typedef __attribute__((ext_vector_type(8))) short short8;
typedef __attribute__((ext_vector_type(4))) float f32x4;

#define MFMA16 __builtin_amdgcn_mfma_f32_16x16x32_bf16

// dtype-flagged external-input load: flag=1 -> bf16, flag=0 -> fp32
__device__ inline float ldin(const void* p, size_t i, int bf) {
    if (bf) return __bfloat162float(((const bf16*)p)[i]);
    return ((const float*)p)[i];
}

__device__ inline float gelu_exact(float x) {
    return 0.5f * x * (1.0f + erff(x * 0.70710678118654752f));
}

// ---------------- dtype detector ----------------
__global__ __launch_bounds__(64) void k_detect(const void* __restrict__ x,
                                               int* __restrict__ flag) {
    int i = threadIdx.x;
    size_t idx = (size_t)(2 * i) * 16384;
    unsigned short u = ((const unsigned short*)x)[idx];
    int e = (u >> 7) & 0xFF;
    int plausible = (e == 0) || (e >= 96 && e <= 132);
    unsigned long long m = __ballot(plausible);
    if (i == 0) *flag = (__popcll(m) >= 48) ? 1 : 0;
}

// ---------------- concat [x, x_cont] -> X (fp32) ----------------
__global__ __launch_bounds__(256) void k_concat(const void* __restrict__ x,
                                                const void* __restrict__ xc,
                                                float* __restrict__ X,
                                                const int* __restrict__ flag) {
    const int bf = *flag;
    int i = blockIdx.x * 256 + threadIdx.x;
    int d = i & 63;
    int f = (i >> 6) & 31;
    int b = i >> 11;
    float v = (f < 16) ? ldin(x,  ((size_t)b * 16 + f) * 64 + d, bf)
                       : ldin(xc, ((size_t)b * 16 + (f - 16)) * 64 + d, bf);
    X[i] = v;
}

// ---------------- LayerNorm over last-64 (emits fp32 + bf16) ----------------
__global__ __launch_bounds__(256) void k_ln64(const float* __restrict__ in,
                                              float* __restrict__ out,
                                              bf16* __restrict__ outh,
                                              const void* __restrict__ g,
                                              const void* __restrict__ b,
                                              size_t eoff,
                                              const int* __restrict__ flag) {
    const int bf = *flag;
    int row  = blockIdx.x * 4 + (threadIdx.x >> 6);
    int lane = threadIdx.x & 63;
    float v = in[(size_t)row * 64 + lane];
    float s = v;
    #pragma unroll
    for (int off = 32; off; off >>= 1) s += __shfl_xor(s, off);
    float mean = s * (1.0f / 64.0f);
    float dx = v - mean;
    float s2 = dx * dx;
    #pragma unroll
    for (int off = 32; off; off >>= 1) s2 += __shfl_xor(s2, off);
    float inv = rsqrtf(s2 * (1.0f / 64.0f) + LNEPS);
    float o = dx * inv * ldin(g, eoff + lane, bf) + ldin(b, eoff + lane, bf);
    out[(size_t)row * 64 + lane]  = o;
    outh[(size_t)row * 64 + lane] = __float2bfloat16(o);
}

// ---------------- LayerNorm over 2048 (emits fp32 + bf16) ----------------
__global__ __launch_bounds__(256) void k_ln_row(const float* __restrict__ in,
                                                float* __restrict__ out,
                                                bf16* __restrict__ outh,
                                                const void* __restrict__ g,
                                                const void* __restrict__ b,
                                                size_t eoff,
                                                const int* __restrict__ flag) {
    const int bf = *flag;
    const int row = blockIdx.x, tid = threadIdx.x;
    __shared__ float red[4];
    const float* r = in + (size_t)row * DROW;
    float v[8];
    float s = 0.f;
    #pragma unroll
    for (int i = 0; i < 8; ++i) { v[i] = r[tid + i * 256]; s += v[i]; }
    #pragma unroll
    for (int off = 32; off; off >>= 1) s += __shfl_xor(s, off);
    if ((tid & 63) == 0) red[tid >> 6] = s;
    __syncthreads();
    float mean = (red[0] + red[1] + red[2] + red[3]) * (1.0f / DROW);
    __syncthreads();
    float s2 = 0.f;
    #pragma unroll
    for (int i = 0; i < 8; ++i) { float dx = v[i] - mean; s2 += dx * dx; }
    #pragma unroll
    for (int off = 32; off; off >>= 1) s2 += __shfl_xor(s2, off);
    if ((tid & 63) == 0) red[tid >> 6] = s2;
    __syncthreads();
    float inv = rsqrtf((red[0] + red[1] + red[2] + red[3]) * (1.0f / DROW) + LNEPS);
    #pragma unroll
    for (int i = 0; i < 8; ++i) {
        int j = tid + i * 256;
        float o = (v[i] - mean) * inv * ldin(g, eoff + j, bf) + ldin(b, eoff + j, bf);
        out[(size_t)row * DROW + j]  = o;
        outh[(size_t)row * DROW + j] = __float2bfloat16(o);
    }
}

// ---------------- transpose+cast external weight: in (RxC, ld=C) -> out bf16 (CxR) ----------------
__global__ __launch_bounds__(256) void k_castT(const void* __restrict__ in, size_t eoff,
                                               int R, int C,
                                               bf16* __restrict__ out,
                                               const int* __restrict__ flag) {
    const int bf = *flag;
    __shared__ bf16 tile[32][33];
    const int tx = threadIdx.x & 31, ty = threadIdx.x >> 5;
    const int bx = blockIdx.x, by = blockIdx.y;
    #pragma unroll
    for (int k = 0; k < 4; ++k) {
        int r = bx * 32 + ty + k * 8;
        int c = by * 32 + tx;
        tile[ty + k * 8][tx] = __float2bfloat16(ldin(in, eoff + (size_t)r * C + c, bf));
    }
    __syncthreads();
    #pragma unroll
    for (int k = 0; k < 4; ++k) {
        int oc = by * 32 + ty + k * 8;
        int orr = bx * 32 + tx;
        out[(size_t)oc * R + orr] = tile[tx][ty + k * 8];
    }
}

// ---------------- transpose bf16 (strided input) ----------------
__global__ __launch_bounds__(256) void k_transpose_bf(const bf16* __restrict__ in, int ld,
                                                      int R, int C,
                                                      bf16* __restrict__ out) {
    __shared__ bf16 tile[32][33];
    const int tx = threadIdx.x & 31, ty = threadIdx.x >> 5;
    const int bx = blockIdx.x, by = blockIdx.y;
    #pragma unroll
    for (int k = 0; k < 4; ++k) {
        int r = bx * 32 + ty + k * 8;
        int c = by * 32 + tx;
        tile[ty + k * 8][tx] = in[(size_t)r * ld + c];
    }
    __syncthreads();
    #pragma unroll
    for (int k = 0; k < 4; ++k) {
        int oc = by * 32 + ty + k * 8;
        int orr = bx * 32 + tx;
        out[(size_t)oc * R + orr] = tile[tx][ty + k * 8];
    }
}

// ---------------- MFMA GEMM: C = alpha * A @ Bt^T (+bias)(+addend) ----------------
template <int WM, int WN, bool OBF>
__global__ __launch_bounds__(256) void k_mfma(
    int M, int N, int K,
    const bf16* __restrict__ A, int lda, long long sA,
    const bf16* __restrict__ Bt, int ldb, long long sB,
    void* __restrict__ C, int ldc, long long sC,
    float alpha,
    const void* __restrict__ bias, size_t biasOff,
    const float* __restrict__ addend, int ldadd,
    const int* __restrict__ flag)
{
    constexpr int TM = WM * 64, TN = WN * 64;
    const int z = blockIdx.z;
    A  += (size_t)z * sA;
    Bt += (size_t)z * sB;
    const int m0 = blockIdx.y * TM, n0 = blockIdx.x * TN;
    const int tid = threadIdx.x, lane = tid & 63, wave = tid >> 6;
    const int wy = wave / WN, wx = wave % WN;
    __shared__ short As[TM][72];
    __shared__ short Bs[TN][72];
    f32x4 acc[4][4] = {};
    const int row8 = tid >> 3, chunk = (tid & 7) * 8;
    for (int k0 = 0; k0 < K; k0 += 64) {
        #pragma unroll
        for (int i = 0; i < TM / 32; ++i) {
            int r = i * 32 + row8;
            *(short8*)&As[r][chunk] =
                *(const short8*)(A + (size_t)(m0 + r) * lda + k0 + chunk);
        }
        #pragma unroll
        for (int i = 0; i < TN / 32; ++i) {
            int r = i * 32 + row8;
            *(short8*)&Bs[r][chunk] =
                *(const short8*)(Bt + (size_t)(n0 + r) * ldb + k0 + chunk);
        }
        __syncthreads();
        #pragma unroll
        for (int ks = 0; ks < 64; ks += 32) {
            short8 af[4], bfr[4];
            #pragma unroll
            for (int mt = 0; mt < 4; ++mt)
                af[mt] = *(const short8*)&As[wy * 64 + mt * 16 + (lane & 15)][ks + (lane >> 4) * 8];
            #pragma unroll
            for (int nt = 0; nt < 4; ++nt)
                bfr[nt] = *(const short8*)&Bs[wx * 64 + nt * 16 + (lane & 15)][ks + (lane >> 4) * 8];
            #pragma unroll
            for (int mt = 0; mt < 4; ++mt)
                #pragma unroll
                for (int nt = 0; nt < 4; ++nt)
                    acc[mt][nt] = MFMA16(af[mt], bfr[nt], acc[mt][nt], 0, 0, 0);
        }
        __syncthreads();
    }
    const int bfl = bias ? *flag : 0;
    #pragma unroll
    for (int mt = 0; mt < 4; ++mt) {
        #pragma unroll
        for (int r = 0; r < 4; ++r) {
            int m = m0 + wy * 64 + mt * 16 + (lane >> 4) * 4 + r;
            #pragma unroll
            for (int nt = 0; nt < 4; ++nt) {
                int n = n0 + wx * 64 + nt * 16 + (lane & 15);
                float v = acc[mt][nt][r] * alpha;
                if (bias)   v += ldin(bias, biasOff + n, bfl);
                if (addend) v += addend[(size_t)m * ldadd + n];
                size_t idx = (size_t)z * sC + (size_t)m * ldc + n;
                if constexpr (OBF) ((bf16*)C)[idx] = __float2bfloat16(v);
                else               ((float*)C)[idx] = v;
            }
        }
    }
}

// ---------------- fused col QKV-proj + attention: one wave per (sample, head) ----------------
// Xh [65536 x 64] bf16; Wt = c_wqkv^T [1536 x 64] bf16 (L2-hot); Oh [65536 x 512]
__global__ __launch_bounds__(256) void k_col_qkv_attn(
    const bf16* __restrict__ Xh, const bf16* __restrict__ Wt,
    bf16* __restrict__ Oh)
{
    __shared__ __align__(16) short qs[4][32][72];
    __shared__ __align__(16) short ks2[4][32][72];
    __shared__ __align__(16) short vs2[4][32][72];
    const int tid = threadIdx.x, lane = tid & 63, wave = tid >> 6;
    const int task = blockIdx.x * 4 + wave;   // sample*8 + head
    const int s = task >> 3, h = task & 7;
    const int l15 = lane & 15, quad = lane >> 4;

    // X A-frags (shared by Q,K,V projections)
    short8 xa[2][2];
    #pragma unroll
    for (int mt = 0; mt < 2; ++mt)
        #pragma unroll
        for (int kc = 0; kc < 2; ++kc)
            xa[mt][kc] = *(const short8*)(Xh + (size_t)(s * 32 + mt * 16 + l15) * 64 + kc * 32 + quad * 8);

    // Q,K,V = X @ W_head  (each 32x64), results to LDS in [seq][dim] bf16
    #pragma unroll
    for (int m3 = 0; m3 < 3; ++m3) {
        f32x4 c[2][4] = {};
        const bf16* wbase = Wt + (size_t)(m3 * 512 + h * 64) * 64;
        #pragma unroll
        for (int nt = 0; nt < 4; ++nt) {
            short8 b0 = *(const short8*)(wbase + (size_t)(nt * 16 + l15) * 64 + quad * 8);
            short8 b1 = *(const short8*)(wbase + (size_t)(nt * 16 + l15) * 64 + 32 + quad * 8);
            #pragma unroll
            for (int mt = 0; mt < 2; ++mt) {
                c[mt][nt] = MFMA16(xa[mt][0], b0, c[mt][nt], 0, 0, 0);
                c[mt][nt] = MFMA16(xa[mt][1], b1, c[mt][nt], 0, 0, 0);
            }
        }
        short (*dst)[72] = (m3 == 0) ? qs[wave] : (m3 == 1) ? ks2[wave] : vs2[wave];
        #pragma unroll
        for (int mt = 0; mt < 2; ++mt)
            #pragma unroll
            for (int nt = 0; nt < 4; ++nt)
                #pragma unroll
                for (int r = 0; r < 4; ++r)
                    *(bf16*)&dst[mt * 16 + quad * 4 + r][nt * 16 + l15] =
                        __float2bfloat16(c[mt][nt][r]);
    }
    __syncthreads();

    // S = Q @ K^T (32x32)
    f32x4 S[2][2] = {};
    #pragma unroll
    for (int mt = 0; mt < 2; ++mt) {
        short8 qa0 = *(const short8*)&qs[wave][mt * 16 + l15][quad * 8];
        short8 qa1 = *(const short8*)&qs[wave][mt * 16 + l15][32 + quad * 8];
        #pragma unroll
        for (int nt = 0; nt < 2; ++nt) {
            short8 kb0 = *(const short8*)&ks2[wave][nt * 16 + l15][quad * 8];
            short8 kb1 = *(const short8*)&ks2[wave][nt * 16 + l15][32 + quad * 8];
            S[mt][nt] = MFMA16(qa0, kb0, S[mt][nt], 0, 0, 0);
            S[mt][nt] = MFMA16(qa1, kb1, S[mt][nt], 0, 0, 0);
        }
    }
    // softmax rows (row = mt*16+quad*4+ri; 32 cols over l15 x 2 ntiles); P -> qs (reuse)
    #pragma unroll
    for (int mt = 0; mt < 2; ++mt) {
        #pragma unroll
        for (int ri = 0; ri < 4; ++ri) {
            float l0 = S[mt][0][ri] * 0.125f, l1 = S[mt][1][ri] * 0.125f;
            float m = fmaxf(l0, l1);
            #pragma unroll
            for (int msk = 1; msk < 16; msk <<= 1) m = fmaxf(m, __shfl_xor(m, msk));
            float e0 = __expf(l0 - m), e1 = __expf(l1 - m);
            float sum = e0 + e1;
            #pragma unroll
            for (int msk = 1; msk < 16; msk <<= 1) sum += __shfl_xor(sum, msk);
            float inv = 1.0f / sum;
            int row = mt * 16 + quad * 4 + ri;
            *(bf16*)&qs[wave][row][l15]      = __float2bfloat16(e0 * inv);
            *(bf16*)&qs[wave][row][16 + l15] = __float2bfloat16(e1 * inv);
        }
    }
    __syncthreads();

    // O = P @ V
    short8 pa[2];
    #pragma unroll
    for (int mt = 0; mt < 2; ++mt)
        pa[mt] = *(const short8*)&qs[wave][mt * 16 + l15][quad * 8];
    f32x4 O[2][4] = {};
    #pragma unroll
    for (int nt = 0; nt < 4; ++nt) {
        short8 vb;
        #pragma unroll
        for (int j = 0; j < 8; ++j) vb[j] = vs2[wave][quad * 8 + j][nt * 16 + l15];
        #pragma unroll
        for (int mt = 0; mt < 2; ++mt)
            O[mt][nt] = MFMA16(pa[mt], vb, O[mt][nt], 0, 0, 0);
    }
    #pragma unroll
    for (int mt = 0; mt < 2; ++mt)
        #pragma unroll
        for (int nt = 0; nt < 4; ++nt)
            #pragma unroll
            for (int ri = 0; ri < 4; ++ri) {
                size_t row = (size_t)s * 32 + mt * 16 + quad * 4 + ri;
                Oh[row * 512 + h * 64 + nt * 16 + l15] = __float2bfloat16(O[mt][nt][ri]);
            }
}

// ---------------- flash row attention: block = (q-tile 64, head), wave = 16 q-rows ----------------
// QKV [2048 x 1536] bf16 (Q at col h*64, K at 512+h*64); Vt [512 x 2048] bf16; O [2048 x 512]
__global__ __launch_bounds__(256) void k_flash_row(
    const bf16* __restrict__ QKV, const bf16* __restrict__ Vt,
    bf16* __restrict__ O)
{
    __shared__ __align__(16) short Ks[128][72];
    __shared__ __align__(16) short Ps[4][16][136];
    const int tid = threadIdx.x, lane = tid & 63, wave = tid >> 6;
    const int h = blockIdx.y;
    const int q0 = blockIdx.x * 64 + wave * 16;
    const int l15 = lane & 15, quad = lane >> 4;

    short8 qa[2];
    #pragma unroll
    for (int kc = 0; kc < 2; ++kc)
        qa[kc] = *(const short8*)(QKV + (size_t)(q0 + l15) * 1536 + h * 64 + kc * 32 + quad * 8);

    float mi[4], li[4];
    #pragma unroll
    for (int r = 0; r < 4; ++r) { mi[r] = -1e30f; li[r] = 0.f; }
    f32x4 Oa[4] = {};

    for (int j = 0; j < 16; ++j) {
        // stage K-tile [128 x 64]
        #pragma unroll
        for (int it = 0; it < 4; ++it) {
            int idx = tid + it * 256;
            int row = idx >> 3, ch = (idx & 7) * 8;
            *(short8*)&Ks[row][ch] =
                *(const short8*)(QKV + (size_t)(j * 128 + row) * 1536 + 512 + h * 64 + ch);
        }
        __syncthreads();
        // S = Q @ K_j^T  (16 x 128)
        f32x4 s[8] = {};
        #pragma unroll
        for (int nt = 0; nt < 8; ++nt) {
            short8 kb0 = *(const short8*)&Ks[nt * 16 + l15][quad * 8];
            short8 kb1 = *(const short8*)&Ks[nt * 16 + l15][32 + quad * 8];
            s[nt] = MFMA16(qa[0], kb0, s[nt], 0, 0, 0);
            s[nt] = MFMA16(qa[1], kb1, s[nt], 0, 0, 0);
        }
        // online softmax; P -> Ps bf16
        #pragma unroll
        for (int r = 0; r < 4; ++r) {
            float mt = -1e30f;
            #pragma unroll
            for (int nt = 0; nt < 8; ++nt) { s[nt][r] *= 0.125f; mt = fmaxf(mt, s[nt][r]); }
            #pragma unroll
            for (int msk = 1; msk < 16; msk <<= 1) mt = fmaxf(mt, __shfl_xor(mt, msk));
            float mn = fmaxf(mi[r], mt);
            float alpha = __expf(mi[r] - mn);
            float ls = 0.f;
            #pragma unroll
            for (int nt = 0; nt < 8; ++nt) { float p = __expf(s[nt][r] - mn); s[nt][r] = p; ls += p; }
            #pragma unroll
            for (int msk = 1; msk < 16; msk <<= 1) ls += __shfl_xor(ls, msk);
            li[r] = li[r] * alpha + ls;
            mi[r] = mn;
            #pragma unroll
            for (int nt = 0; nt < 4; ++nt) Oa[nt][r] *= alpha;
            int row = quad * 4 + r;
            #pragma unroll
            for (int nt = 0; nt < 8; ++nt)
                *(bf16*)&Ps[wave][row][nt * 16 + l15] = __float2bfloat16(s[nt][r]);
        }
        __syncthreads();
        // O += P @ V_j   (V_j B-frags straight from global Vt)
        short8 pa[4];
        #pragma unroll
        for (int kc = 0; kc < 4; ++kc)
            pa[kc] = *(const short8*)&Ps[wave][l15][kc * 32 + quad * 8];
        #pragma unroll
        for (int nt = 0; nt < 4; ++nt) {
            #pragma unroll
            for (int kc = 0; kc < 4; ++kc) {
                short8 vb = *(const short8*)(Vt + (size_t)(h * 64 + nt * 16 + l15) * 2048 +
                                             j * 128 + kc * 32 + quad * 8);
                Oa[nt] = MFMA16(pa[kc], vb, Oa[nt], 0, 0, 0);
            }
        }
        __syncthreads();
    }
    #pragma unroll
    for (int nt = 0; nt < 4; ++nt)
        #pragma unroll
        for (int r = 0; r < 4; ++r) {
            float v = Oa[nt][r] / li[r];
            O[(size_t)(q0 + quad * 4 + r) * 512 + h * 64 + nt * 16 + l15] = __float2bfloat16(v);
        }
}

// ---------------- GEGLU row: H fp32 [2048x2048] -> P bf16 [2048x1024] ----------------
__global__ __launch_bounds__(256) void k_geglu_row(const float* __restrict__ H,
                                                   bf16* __restrict__ P) {
    int i = blockIdx.x * 256 + threadIdx.x;
    int r = i >> 10, j = i & 1023;
    float a = H[(size_t)r * 2048 + j];
    float g = H[(size_t)r * 2048 + 1024 + j];
    P[i] = __float2bfloat16(a * gelu_exact(g));
}

// ---------------- GEGLU col: H1 bf16 [65536x512] -> Pc bf16 [65536x256] ----------------
__global__ __launch_bounds__(256) void k_geglu_col(const bf16* __restrict__ H,
                                                   bf16* __restrict__ P) {
    int i = blockIdx.x * 256 + threadIdx.x;
    int r = i >> 8, j = i & 255;
    float a = __bfloat162float(H[(size_t)r * 512 + j]);
    float g = __bfloat162float(H[(size_t)r * 512 + 256 + j]);
    P[i] = __float2bfloat16(a * gelu_exact(g));
}

// ---------------- final cast fp32 -> output dtype ----------------
__global__ __launch_bounds__(256) void k_cast_out(const float* __restrict__ X,
                                                  void* __restrict__ out,
                                                  const int* __restrict__ flag) {
    const int bf = *flag;
    int i = blockIdx.x * 256 + threadIdx.x;
    if (bf) ((bf16*)out)[i] = __float2bfloat16(X[i]);
    else    ((float*)out)[i] = X[i];
}

// =====================================================================
extern "C" void kernel_launch(void* const* d_in, const int* in_sizes, int n_in,
                              void* d_out, int out_size, void* d_ws, size_t ws_size,
                              hipStream_t stream) {
    const void* x       = d_in[0];
    const void* x_cont  = d_in[1];
    const void* c_ln1_g = d_in[2];
    const void* c_ln1_b = d_in[3];
    const void* c_wqkv  = d_in[4];
    const void* c_wo_w  = d_in[5];
    const void* c_wo_b  = d_in[6];
    const void* c_ln2_g = d_in[7];
    const void* c_ln2_b = d_in[8];
    const void* c_w1    = d_in[9];
    const void* c_b1    = d_in[10];
    const void* c_w2    = d_in[11];
    const void* c_b2    = d_in[12];
    const void* r_ln1_g = d_in[13];
    const void* r_ln1_b = d_in[14];
    const void* r_wqkv  = d_in[15];
    const void* r_wo_w  = d_in[16];
    const void* r_wo_b  = d_in[17];
    const void* r_ln2_g = d_in[18];
    const void* r_ln2_b = d_in[19];
    const void* r_w1    = d_in[20];
    const void* r_b1    = d_in[21];
    const void* r_w2    = d_in[22];
    const void* r_b2    = d_in[23];

    const size_t NX = (size_t)BD * NF * DIMC;        // 4,194,304
    float* X   = (float*)d_ws;
    float* XN  = X   + NX;
    float* ACC = XN  + NX;
    bf16* XNh  = (bf16*)(ACC + NX);                   // NX bf16
    bf16* WtR  = XNh + NX;                            // row weights (<=2048x2048)
    bf16* WcQ  = WtR + (size_t)2048 * 2048;           // 1536x64
    bf16* WcO  = WcQ + 98304;                         // 64x512
    bf16* Wc1  = WcO + 32768;                         // 512x64
    bf16* Wc2  = Wc1 + 32768;                         // 64x256
    bf16* Sc   = Wc2 + 16384;                         // scratch union base
    // col block:
    bf16* OhC  = Sc;                                  // 65536x512 = 33,554,432
    bf16* H1   = Sc;                                  // (OhC dead by then)
    bf16* Pc   = Sc + 33554432;                       // 65536x256
    // row block (fits in first 31 MB of Sc):
    bf16* QKVhR = Sc;                                 // 2048x1536
    bf16* VtR   = QKVhR + 3145728;                    // 512x2048
    bf16* OhR   = VtR + 1048576;                      // 2048x512
    bf16* PmR   = OhR + 1048576;                      // 2048x1024
    float* Hrow = (float*)(PmR + 2097152);            // 2048x2048 fp32
    char* scEnd = (char*)Sc + (size_t)(33554432 + 16777216) * 2;  // 100.7 MB
    int*  flag  = (int*)scEnd;
    const size_t need = (size_t)(scEnd + 64 - (char*)d_ws);
    if (ws_size < need) return;

    k_detect<<<1, 64, 0, stream>>>(x, flag);
    k_concat<<<16384, 256, 0, stream>>>(x, x_cont, X, flag);

    for (int d = 0; d < 4; ++d) {
        // ================= col block =================
        k_ln64<<<16384, 256, 0, stream>>>(X, XN, XNh, c_ln1_g, c_ln1_b, (size_t)d * 64, flag);
        k_castT<<<dim3(2, 48), 256, 0, stream>>>(c_wqkv, (size_t)d * 64 * 1536, 64, 1536, WcQ, flag);
        k_col_qkv_attn<<<4096, 256, 0, stream>>>(XNh, WcQ, OhC);
        k_castT<<<dim3(16, 2), 256, 0, stream>>>(c_wo_w, (size_t)d * 512 * 64, 512, 64, WcO, flag);
        k_mfma<4, 1, false><<<dim3(1, 256, 1), 256, 0, stream>>>(
            65536, 64, 512, OhC, 512, 0, WcO, 512, 0,
            ACC, 64, 0, 1.0f, c_wo_b, (size_t)d * 64, XN, 64, flag);
        k_ln64<<<16384, 256, 0, stream>>>(ACC, XN, XNh, c_ln2_g, c_ln2_b, (size_t)d * 64, flag);
        k_castT<<<dim3(2, 16), 256, 0, stream>>>(c_w1, (size_t)d * 64 * 512, 64, 512, Wc1, flag);
        k_mfma<2, 2, true><<<dim3(4, 512, 1), 256, 0, stream>>>(
            65536, 512, 64, XNh, 64, 0, Wc1, 64, 0,
            H1, 512, 0, 1.0f, c_b1, (size_t)d * 512, nullptr, 0, flag);
        k_geglu_col<<<65536, 256, 0, stream>>>(H1, Pc);
        k_castT<<<dim3(8, 2), 256, 0, stream>>>(c_w2, (size_t)d * 256 * 64, 256, 64, Wc2, flag);
        k_mfma<4, 1, false><<<dim3(1, 256, 1), 256, 0, stream>>>(
            65536, 64, 256, Pc, 256, 0, Wc2, 256, 0,
            X, 64, 0, 1.0f, c_b2, (size_t)d * 64, XN, 64, flag);

        // ================= row block =================
        k_ln_row<<<BD, 256, 0, stream>>>(X, XN, XNh, r_ln1_g, r_ln1_b, (size_t)d * DROW, flag);
        k_castT<<<dim3(64, 48), 256, 0, stream>>>(r_wqkv, (size_t)d * 2048 * 1536, 2048, 1536, WtR, flag);
        k_mfma<2, 2, true><<<dim3(12, 16, 1), 256, 0, stream>>>(
            2048, 1536, 2048, XNh, 2048, 0, WtR, 2048, 0,
            QKVhR, 1536, 0, 1.0f, nullptr, 0, nullptr, 0, flag);
        k_transpose_bf<<<dim3(64, 16), 256, 0, stream>>>(QKVhR + 1024, 1536, 2048, 512, VtR);
        k_flash_row<<<dim3(32, 8), 256, 0, stream>>>(QKVhR, VtR, OhR);
        k_castT<<<dim3(16, 64), 256, 0, stream>>>(r_wo_w, (size_t)d * 512 * 2048, 512, 2048, WtR, flag);
        k_mfma<2, 2, false><<<dim3(16, 16, 1), 256, 0, stream>>>(
            2048, 2048, 512, OhR, 512, 0, WtR, 512, 0,
            ACC, 2048, 0, 1.0f, r_wo_b, (size_t)d * DROW, XN, 2048, flag);
        k_ln_row<<<BD, 256, 0, stream>>>(ACC, XN, XNh, r_ln2_g, r_ln2_b, (size_t)d * DROW, flag);
        k_castT<<<dim3(64, 64), 256, 0, stream>>>(r_w1, (size_t)d * 2048 * 2048, 2048, 2048, WtR, flag);
        k_mfma<2, 2, false><<<dim3(16, 16, 1), 256, 0, stream>>>(
            2048, 2048, 2048, XNh, 2048, 0, WtR, 2048, 0,
            Hrow, 2048, 0, 1.0f, r_b1, (size_t)d * 2048, nullptr, 0, flag);
        k_geglu_row<<<8192, 256, 0, stream>>>(Hrow, PmR);
        k_castT<<<dim3(32, 64), 256, 0, stream>>>(r_w2, (size_t)d * 1024 * 2048, 1024, 2048, WtR, flag);
        k_mfma<2, 2, false><<<dim3(16, 16, 1), 256, 0, stream>>>(
            2048, 2048, 1024, PmR, 1024, 0, WtR, 1024, 0,
            X, 2048, 0, 1.0f, r_b2, (size_t)d * DROW, XN, 2048, flag);
    }

    k_cast_out<<<16384, 256, 0, stream>>>(X, d_out, flag);
}

// Round 7
// 2382.017 us; speedup vs baseline: 4.9688x; 1.0595x over previous
//
#include <hip/hip_runtime.h>
#include <hip/hip_bf16.h>
#include <cstddef>

#define BD    2048
#define NF    32
#define DIMC  64
#define HEADS 8
#define DROW  2048
#define LNEPS 1e-5f

typedef __hip_bfloat16 bf16;
typedef __attribute__((ext_vector_type(8))) short short8;
typedef __attribute__((ext_vector_type(4))) float f32x4;

#define MFMA16 __builtin_amdgcn_mfma_f32_16x16x32_bf16

__device__ inline float ldin(const void* p, size_t i, int bf) {
    if (bf) return __bfloat162float(((const bf16*)p)[i]);
    return ((const float*)p)[i];
}

__device__ inline float gelu_exact(float x) {
    return 0.5f * x * (1.0f + erff(x * 0.70710678118654752f));
}

// ---------------- dtype detector ----------------
__global__ __launch_bounds__(64) void k_detect(const void* __restrict__ x,
                                               int* __restrict__ flag) {
    int i = threadIdx.x;
    size_t idx = (size_t)(2 * i) * 16384;
    unsigned short u = ((const unsigned short*)x)[idx];
    int e = (u >> 7) & 0xFF;
    int plausible = (e == 0) || (e >= 96 && e <= 132);
    unsigned long long m = __ballot(plausible);
    if (i == 0) *flag = (__popcll(m) >= 48) ? 1 : 0;
}

// ---------------- concat ----------------
__global__ __launch_bounds__(256) void k_concat(const void* __restrict__ x,
                                                const void* __restrict__ xc,
                                                float* __restrict__ X,
                                                const int* __restrict__ flag) {
    const int bf = *flag;
    int i = blockIdx.x * 256 + threadIdx.x;
    int d = i & 63;
    int f = (i >> 6) & 31;
    int b = i >> 11;
    float v = (f < 16) ? ldin(x,  ((size_t)b * 16 + f) * 64 + d, bf)
                       : ldin(xc, ((size_t)b * 16 + (f - 16)) * 64 + d, bf);
    X[i] = v;
}

// ---------------- LayerNorm 64 (fp32 + bf16 out) ----------------
__global__ __launch_bounds__(256) void k_ln64(const float* __restrict__ in,
                                              float* __restrict__ out,
                                              bf16* __restrict__ outh,
                                              const void* __restrict__ g,
                                              const void* __restrict__ b,
                                              size_t eoff,
                                              const int* __restrict__ flag) {
    const int bf = *flag;
    int row  = blockIdx.x * 4 + (threadIdx.x >> 6);
    int lane = threadIdx.x & 63;
    float v = in[(size_t)row * 64 + lane];
    float s = v;
    #pragma unroll
    for (int off = 32; off; off >>= 1) s += __shfl_xor(s, off);
    float mean = s * (1.0f / 64.0f);
    float dx = v - mean;
    float s2 = dx * dx;
    #pragma unroll
    for (int off = 32; off; off >>= 1) s2 += __shfl_xor(s2, off);
    float inv = rsqrtf(s2 * (1.0f / 64.0f) + LNEPS);
    float o = dx * inv * ldin(g, eoff + lane, bf) + ldin(b, eoff + lane, bf);
    out[(size_t)row * 64 + lane]  = o;
    outh[(size_t)row * 64 + lane] = __float2bfloat16(o);
}

// ---------------- LayerNorm 2048 (fp32 + bf16 out) ----------------
__global__ __launch_bounds__(256) void k_ln_row(const float* __restrict__ in,
                                                float* __restrict__ out,
                                                bf16* __restrict__ outh,
                                                const void* __restrict__ g,
                                                const void* __restrict__ b,
                                                size_t eoff,
                                                const int* __restrict__ flag) {
    const int bf = *flag;
    const int row = blockIdx.x, tid = threadIdx.x;
    __shared__ float red[4];
    const float* r = in + (size_t)row * DROW;
    float v[8];
    float s = 0.f;
    #pragma unroll
    for (int i = 0; i < 8; ++i) { v[i] = r[tid + i * 256]; s += v[i]; }
    #pragma unroll
    for (int off = 32; off; off >>= 1) s += __shfl_xor(s, off);
    if ((tid & 63) == 0) red[tid >> 6] = s;
    __syncthreads();
    float mean = (red[0] + red[1] + red[2] + red[3]) * (1.0f / DROW);
    __syncthreads();
    float s2 = 0.f;
    #pragma unroll
    for (int i = 0; i < 8; ++i) { float dx = v[i] - mean; s2 += dx * dx; }
    #pragma unroll
    for (int off = 32; off; off >>= 1) s2 += __shfl_xor(s2, off);
    if ((tid & 63) == 0) red[tid >> 6] = s2;
    __syncthreads();
    float inv = rsqrtf((red[0] + red[1] + red[2] + red[3]) * (1.0f / DROW) + LNEPS);
    #pragma unroll
    for (int i = 0; i < 8; ++i) {
        int j = tid + i * 256;
        float o = (v[i] - mean) * inv * ldin(g, eoff + j, bf) + ldin(b, eoff + j, bf);
        out[(size_t)row * DROW + j]  = o;
        outh[(size_t)row * DROW + j] = __float2bfloat16(o);
    }
}

// ---------------- transpose+cast weight ----------------
__global__ __launch_bounds__(256) void k_castT(const void* __restrict__ in, size_t eoff,
                                               int R, int C,
                                               bf16* __restrict__ out,
                                               const int* __restrict__ flag) {
    const int bf = *flag;
    __shared__ bf16 tile[32][33];
    const int tx = threadIdx.x & 31, ty = threadIdx.x >> 5;
    const int bx = blockIdx.x, by = blockIdx.y;
    #pragma unroll
    for (int k = 0; k < 4; ++k) {
        int r = bx * 32 + ty + k * 8;
        int c = by * 32 + tx;
        tile[ty + k * 8][tx] = __float2bfloat16(ldin(in, eoff + (size_t)r * C + c, bf));
    }
    __syncthreads();
    #pragma unroll
    for (int k = 0; k < 4; ++k) {
        int oc = by * 32 + ty + k * 8;
        int orr = bx * 32 + tx;
        out[(size_t)oc * R + orr] = tile[tx][ty + k * 8];
    }
}

// ---------------- transpose bf16 ----------------
__global__ __launch_bounds__(256) void k_transpose_bf(const bf16* __restrict__ in, int ld,
                                                      int R, int C,
                                                      bf16* __restrict__ out) {
    __shared__ bf16 tile[32][33];
    const int tx = threadIdx.x & 31, ty = threadIdx.x >> 5;
    const int bx = blockIdx.x, by = blockIdx.y;
    #pragma unroll
    for (int k = 0; k < 4; ++k) {
        int r = bx * 32 + ty + k * 8;
        int c = by * 32 + tx;
        tile[ty + k * 8][tx] = in[(size_t)r * ld + c];
    }
    __syncthreads();
    #pragma unroll
    for (int k = 0; k < 4; ++k) {
        int oc = by * 32 + ty + k * 8;
        int orr = bx * 32 + tx;
        out[(size_t)oc * R + orr] = tile[tx][ty + k * 8];
    }
}

// ---------------- MFMA GEMM (full-K, epilogue fused) ----------------
template <int WM, int WN, bool OBF>
__global__ __launch_bounds__(256) void k_mfma(
    int M, int N, int K,
    const bf16* __restrict__ A, int lda, long long sA,
    const bf16* __restrict__ Bt, int ldb, long long sB,
    void* __restrict__ C, int ldc, long long sC,
    float alpha,
    const void* __restrict__ bias, size_t biasOff,
    const float* __restrict__ addend, int ldadd,
    const int* __restrict__ flag)
{
    constexpr int TM = WM * 64, TN = WN * 64;
    const int z = blockIdx.z;
    A  += (size_t)z * sA;
    Bt += (size_t)z * sB;
    const int m0 = blockIdx.y * TM, n0 = blockIdx.x * TN;
    const int tid = threadIdx.x, lane = tid & 63, wave = tid >> 6;
    const int wy = wave / WN, wx = wave % WN;
    __shared__ short As[TM][72];
    __shared__ short Bs[TN][72];
    f32x4 acc[4][4] = {};
    const int row8 = tid >> 3, chunk = (tid & 7) * 8;
    for (int k0 = 0; k0 < K; k0 += 64) {
        #pragma unroll
        for (int i = 0; i < TM / 32; ++i) {
            int r = i * 32 + row8;
            *(short8*)&As[r][chunk] =
                *(const short8*)(A + (size_t)(m0 + r) * lda + k0 + chunk);
        }
        #pragma unroll
        for (int i = 0; i < TN / 32; ++i) {
            int r = i * 32 + row8;
            *(short8*)&Bs[r][chunk] =
                *(const short8*)(Bt + (size_t)(n0 + r) * ldb + k0 + chunk);
        }
        __syncthreads();
        #pragma unroll
        for (int ks = 0; ks < 64; ks += 32) {
            short8 af[4], bfr[4];
            #pragma unroll
            for (int mt = 0; mt < 4; ++mt)
                af[mt] = *(const short8*)&As[wy * 64 + mt * 16 + (lane & 15)][ks + (lane >> 4) * 8];
            #pragma unroll
            for (int nt = 0; nt < 4; ++nt)
                bfr[nt] = *(const short8*)&Bs[wx * 64 + nt * 16 + (lane & 15)][ks + (lane >> 4) * 8];
            #pragma unroll
            for (int mt = 0; mt < 4; ++mt)
                #pragma unroll
                for (int nt = 0; nt < 4; ++nt)
                    acc[mt][nt] = MFMA16(af[mt], bfr[nt], acc[mt][nt], 0, 0, 0);
        }
        __syncthreads();
    }
    const int bfl = bias ? *flag : 0;
    #pragma unroll
    for (int mt = 0; mt < 4; ++mt) {
        #pragma unroll
        for (int r = 0; r < 4; ++r) {
            int m = m0 + wy * 64 + mt * 16 + (lane >> 4) * 4 + r;
            #pragma unroll
            for (int nt = 0; nt < 4; ++nt) {
                int n = n0 + wx * 64 + nt * 16 + (lane & 15);
                float v = acc[mt][nt][r] * alpha;
                if (bias)   v += ldin(bias, biasOff + n, bfl);
                if (addend) v += addend[(size_t)m * ldadd + n];
                size_t idx = (size_t)z * sC + (size_t)m * ldc + n;
                if constexpr (OBF) ((bf16*)C)[idx] = __float2bfloat16(v);
                else               ((float*)C)[idx] = v;
            }
        }
    }
}

// ---------------- MFMA GEMM split-K: z = K-chunk, fp32 partials ----------------
template <int WM, int WN>
__global__ __launch_bounds__(256) void k_mfma_sk(
    int M, int N, int KC,
    const bf16* __restrict__ A, int lda,
    const bf16* __restrict__ Bt, int ldb,
    float* __restrict__ Cp, long long pstride)
{
    constexpr int TM = WM * 64, TN = WN * 64;
    const int z = blockIdx.z;
    const int m0 = blockIdx.y * TM, n0 = blockIdx.x * TN;
    const int tid = threadIdx.x, lane = tid & 63, wave = tid >> 6;
    const int wy = wave / WN, wx = wave % WN;
    __shared__ short As[TM][72];
    __shared__ short Bs[TN][72];
    f32x4 acc[4][4] = {};
    const int row8 = tid >> 3, chunk = (tid & 7) * 8;
    const int kend = z * KC + KC;
    for (int k0 = z * KC; k0 < kend; k0 += 64) {
        #pragma unroll
        for (int i = 0; i < TM / 32; ++i) {
            int r = i * 32 + row8;
            *(short8*)&As[r][chunk] =
                *(const short8*)(A + (size_t)(m0 + r) * lda + k0 + chunk);
        }
        #pragma unroll
        for (int i = 0; i < TN / 32; ++i) {
            int r = i * 32 + row8;
            *(short8*)&Bs[r][chunk] =
                *(const short8*)(Bt + (size_t)(n0 + r) * ldb + k0 + chunk);
        }
        __syncthreads();
        #pragma unroll
        for (int ks = 0; ks < 64; ks += 32) {
            short8 af[4], bfr[4];
            #pragma unroll
            for (int mt = 0; mt < 4; ++mt)
                af[mt] = *(const short8*)&As[wy * 64 + mt * 16 + (lane & 15)][ks + (lane >> 4) * 8];
            #pragma unroll
            for (int nt = 0; nt < 4; ++nt)
                bfr[nt] = *(const short8*)&Bs[wx * 64 + nt * 16 + (lane & 15)][ks + (lane >> 4) * 8];
            #pragma unroll
            for (int mt = 0; mt < 4; ++mt)
                #pragma unroll
                for (int nt = 0; nt < 4; ++nt)
                    acc[mt][nt] = MFMA16(af[mt], bfr[nt], acc[mt][nt], 0, 0, 0);
        }
        __syncthreads();
    }
    float* Co = Cp + (size_t)z * pstride;
    #pragma unroll
    for (int mt = 0; mt < 4; ++mt)
        #pragma unroll
        for (int r = 0; r < 4; ++r) {
            int m = m0 + wy * 64 + mt * 16 + (lane >> 4) * 4 + r;
            #pragma unroll
            for (int nt = 0; nt < 4; ++nt) {
                int n = n0 + wx * 64 + nt * 16 + (lane & 15);
                Co[(size_t)m * N + n] = acc[mt][nt][r];
            }
        }
}

// ---------------- split-K combine: out = sum partials (+bias)(+addend) ----------------
template <bool OBF>
__global__ __launch_bounds__(256) void k_combine(
    int KS, const float* __restrict__ P, long long pstride, int N,
    void* __restrict__ C,
    const void* __restrict__ bias, size_t biasOff,
    const float* __restrict__ addend,
    const int* __restrict__ flag)
{
    int i = blockIdx.x * 256 + threadIdx.x;
    float v = 0.f;
    for (int z = 0; z < KS; ++z) v += P[(size_t)z * pstride + i];
    if (bias)   v += ldin(bias, biasOff + (size_t)(i % N), bias ? *flag : 0);
    if (addend) v += addend[i];
    if constexpr (OBF) ((bf16*)C)[i] = __float2bfloat16(v);
    else               ((float*)C)[i] = v;
}

// ---------------- fused col QKV-proj + attention (per-wave LDS, no barriers) ----------------
__global__ __launch_bounds__(256) void k_col_qkv_attn(
    const bf16* __restrict__ Xh, const bf16* __restrict__ Wt,
    bf16* __restrict__ Oh)
{
    __shared__ __align__(16) short qs[4][32][72];
    __shared__ __align__(16) short ks2[4][32][72];
    __shared__ __align__(16) short vs2[4][32][72];
    const int tid = threadIdx.x, lane = tid & 63, wave = tid >> 6;
    const int task = blockIdx.x * 4 + wave;   // sample*8 + head
    const int s = task >> 3, h = task & 7;
    const int l15 = lane & 15, quad = lane >> 4;

    short8 xa[2][2];
    #pragma unroll
    for (int mt = 0; mt < 2; ++mt)
        #pragma unroll
        for (int kc = 0; kc < 2; ++kc)
            xa[mt][kc] = *(const short8*)(Xh + (size_t)(s * 32 + mt * 16 + l15) * 64 + kc * 32 + quad * 8);

    #pragma unroll
    for (int m3 = 0; m3 < 3; ++m3) {
        f32x4 c[2][4] = {};
        const bf16* wbase = Wt + (size_t)(m3 * 512 + h * 64) * 64;
        #pragma unroll
        for (int nt = 0; nt < 4; ++nt) {
            short8 b0 = *(const short8*)(wbase + (size_t)(nt * 16 + l15) * 64 + quad * 8);
            short8 b1 = *(const short8*)(wbase + (size_t)(nt * 16 + l15) * 64 + 32 + quad * 8);
            #pragma unroll
            for (int mt = 0; mt < 2; ++mt) {
                c[mt][nt] = MFMA16(xa[mt][0], b0, c[mt][nt], 0, 0, 0);
                c[mt][nt] = MFMA16(xa[mt][1], b1, c[mt][nt], 0, 0, 0);
            }
        }
        short (*dst)[72] = (m3 == 0) ? qs[wave] : (m3 == 1) ? ks2[wave] : vs2[wave];
        #pragma unroll
        for (int mt = 0; mt < 2; ++mt)
            #pragma unroll
            for (int nt = 0; nt < 4; ++nt)
                #pragma unroll
                for (int r = 0; r < 4; ++r)
                    *(bf16*)&dst[mt * 16 + quad * 4 + r][nt * 16 + l15] =
                        __float2bfloat16(c[mt][nt][r]);
    }
    // per-wave LDS: compiler-inserted lgkmcnt waits suffice (no cross-wave sharing)
    f32x4 S[2][2] = {};
    #pragma unroll
    for (int mt = 0; mt < 2; ++mt) {
        short8 qa0 = *(const short8*)&qs[wave][mt * 16 + l15][quad * 8];
        short8 qa1 = *(const short8*)&qs[wave][mt * 16 + l15][32 + quad * 8];
        #pragma unroll
        for (int nt = 0; nt < 2; ++nt) {
            short8 kb0 = *(const short8*)&ks2[wave][nt * 16 + l15][quad * 8];
            short8 kb1 = *(const short8*)&ks2[wave][nt * 16 + l15][32 + quad * 8];
            S[mt][nt] = MFMA16(qa0, kb0, S[mt][nt], 0, 0, 0);
            S[mt][nt] = MFMA16(qa1, kb1, S[mt][nt], 0, 0, 0);
        }
    }
    #pragma unroll
    for (int mt = 0; mt < 2; ++mt) {
        #pragma unroll
        for (int ri = 0; ri < 4; ++ri) {
            float l0 = S[mt][0][ri] * 0.125f, l1 = S[mt][1][ri] * 0.125f;
            float m = fmaxf(l0, l1);
            #pragma unroll
            for (int msk = 1; msk < 16; msk <<= 1) m = fmaxf(m, __shfl_xor(m, msk));
            float e0 = __expf(l0 - m), e1 = __expf(l1 - m);
            float sum = e0 + e1;
            #pragma unroll
            for (int msk = 1; msk < 16; msk <<= 1) sum += __shfl_xor(sum, msk);
            float inv = 1.0f / sum;
            int row = mt * 16 + quad * 4 + ri;
            *(bf16*)&qs[wave][row][l15]      = __float2bfloat16(e0 * inv);
            *(bf16*)&qs[wave][row][16 + l15] = __float2bfloat16(e1 * inv);
        }
    }
    short8 pa[2];
    #pragma unroll
    for (int mt = 0; mt < 2; ++mt)
        pa[mt] = *(const short8*)&qs[wave][mt * 16 + l15][quad * 8];
    f32x4 O[2][4] = {};
    #pragma unroll
    for (int nt = 0; nt < 4; ++nt) {
        short8 vb;
        #pragma unroll
        for (int j = 0; j < 8; ++j) vb[j] = vs2[wave][quad * 8 + j][nt * 16 + l15];
        #pragma unroll
        for (int mt = 0; mt < 2; ++mt)
            O[mt][nt] = MFMA16(pa[mt], vb, O[mt][nt], 0, 0, 0);
    }
    #pragma unroll
    for (int mt = 0; mt < 2; ++mt)
        #pragma unroll
        for (int nt = 0; nt < 4; ++nt)
            #pragma unroll
            for (int ri = 0; ri < 4; ++ri) {
                size_t row = (size_t)s * 32 + mt * 16 + quad * 4 + ri;
                Oh[row * 512 + h * 64 + nt * 16 + l15] = __float2bfloat16(O[mt][nt][ri]);
            }
}

// ---------------- flash row attention v2: K-split, barrier-free ----------------
// grid (32, HEADS, 4); block 256 (4 waves x 16 q-rows). Writes UNNORMALIZED O
// partials (fp32) + (m,l) per row; k_flash_combine finishes.
__global__ __launch_bounds__(256) void k_flash_row(
    const bf16* __restrict__ QKV, const bf16* __restrict__ Vt,
    float* __restrict__ Opart, float* __restrict__ ML)
{
    __shared__ __align__(16) short Ps[4][16][136];
    const int tid = threadIdx.x, lane = tid & 63, wave = tid >> 6;
    const int h = blockIdx.y, z = blockIdx.z;
    const int q0 = blockIdx.x * 64 + wave * 16;
    const int l15 = lane & 15, quad = lane >> 4;

    short8 qa[2];
    #pragma unroll
    for (int kc = 0; kc < 2; ++kc)
        qa[kc] = *(const short8*)(QKV + (size_t)(q0 + l15) * 1536 + h * 64 + kc * 32 + quad * 8);

    float mi[4], li[4];
    #pragma unroll
    for (int r = 0; r < 4; ++r) { mi[r] = -1e30f; li[r] = 0.f; }
    f32x4 Oa[4] = {};

    #pragma unroll
    for (int jj = 0; jj < 4; ++jj) {
        const int j = z * 4 + jj;
        // S = Q @ K_j^T — K B-frags straight from global (row-major [seq][dim])
        f32x4 s[8] = {};
        #pragma unroll
        for (int nt = 0; nt < 8; ++nt) {
            const bf16* krow = QKV + (size_t)(j * 128 + nt * 16 + l15) * 1536 + 512 + h * 64;
            short8 kb0 = *(const short8*)(krow + quad * 8);
            short8 kb1 = *(const short8*)(krow + 32 + quad * 8);
            s[nt] = MFMA16(qa[0], kb0, s[nt], 0, 0, 0);
            s[nt] = MFMA16(qa[1], kb1, s[nt], 0, 0, 0);
        }
        // online softmax (per-wave), P -> Ps (per-wave LDS, no barrier)
        #pragma unroll
        for (int r = 0; r < 4; ++r) {
            float mt = -1e30f;
            #pragma unroll
            for (int nt = 0; nt < 8; ++nt) { s[nt][r] *= 0.125f; mt = fmaxf(mt, s[nt][r]); }
            #pragma unroll
            for (int msk = 1; msk < 16; msk <<= 1) mt = fmaxf(mt, __shfl_xor(mt, msk));
            float mn = fmaxf(mi[r], mt);
            float alpha = __expf(mi[r] - mn);
            float ls = 0.f;
            #pragma unroll
            for (int nt = 0; nt < 8; ++nt) { float p = __expf(s[nt][r] - mn); s[nt][r] = p; ls += p; }
            #pragma unroll
            for (int msk = 1; msk < 16; msk <<= 1) ls += __shfl_xor(ls, msk);
            li[r] = li[r] * alpha + ls;
            mi[r] = mn;
            #pragma unroll
            for (int nt = 0; nt < 4; ++nt) Oa[nt][r] *= alpha;
            int row = quad * 4 + r;
            #pragma unroll
            for (int nt = 0; nt < 8; ++nt)
                *(bf16*)&Ps[wave][row][nt * 16 + l15] = __float2bfloat16(s[nt][r]);
        }
        // O += P @ V_j
        short8 pa[4];
        #pragma unroll
        for (int kc = 0; kc < 4; ++kc)
            pa[kc] = *(const short8*)&Ps[wave][l15][kc * 32 + quad * 8];
        #pragma unroll
        for (int nt = 0; nt < 4; ++nt) {
            #pragma unroll
            for (int kc = 0; kc < 4; ++kc) {
                short8 vb = *(const short8*)(Vt + (size_t)(h * 64 + nt * 16 + l15) * 2048 +
                                             j * 128 + kc * 32 + quad * 8);
                Oa[nt] = MFMA16(pa[kc], vb, Oa[nt], 0, 0, 0);
            }
        }
    }
    float* Op = Opart + (size_t)z * 1048576;
    #pragma unroll
    for (int nt = 0; nt < 4; ++nt)
        #pragma unroll
        for (int r = 0; r < 4; ++r)
            Op[(size_t)(q0 + quad * 4 + r) * 512 + h * 64 + nt * 16 + l15] = Oa[nt][r];
    if (l15 == 0) {
        #pragma unroll
        for (int r = 0; r < 4; ++r) {
            int row = q0 + quad * 4 + r;
            ML[((size_t)(z * 8 + h) * 2048 + row) * 2]     = mi[r];
            ML[((size_t)(z * 8 + h) * 2048 + row) * 2 + 1] = li[r];
        }
    }
}

// ---------------- flash combine: O = sum_z e^{m_z-M} O_z / sum_z e^{m_z-M} l_z ----------------
__global__ __launch_bounds__(256) void k_flash_combine(
    const float* __restrict__ Opart, const float* __restrict__ ML,
    bf16* __restrict__ O)
{
    int i = blockIdx.x * 256 + threadIdx.x;     // 2048*512
    int row = i >> 9, n = i & 511, h = n >> 6;
    float m[4], l[4], M = -1e30f;
    #pragma unroll
    for (int z = 0; z < 4; ++z) {
        m[z] = ML[((size_t)(z * 8 + h) * 2048 + row) * 2];
        l[z] = ML[((size_t)(z * 8 + h) * 2048 + row) * 2 + 1];
        M = fmaxf(M, m[z]);
    }
    float num = 0.f, den = 0.f;
    #pragma unroll
    for (int z = 0; z < 4; ++z) {
        float w = __expf(m[z] - M);
        num += w * Opart[(size_t)z * 1048576 + i];
        den += w * l[z];
    }
    O[i] = __float2bfloat16(num / den);
}

// ---------------- GEGLU row ----------------
__global__ __launch_bounds__(256) void k_geglu_row(const float* __restrict__ H,
                                                   bf16* __restrict__ P) {
    int i = blockIdx.x * 256 + threadIdx.x;
    int r = i >> 10, j = i & 1023;
    float a = H[(size_t)r * 2048 + j];
    float g = H[(size_t)r * 2048 + 1024 + j];
    P[i] = __float2bfloat16(a * gelu_exact(g));
}

// ---------------- GEGLU col ----------------
__global__ __launch_bounds__(256) void k_geglu_col(const bf16* __restrict__ H,
                                                   bf16* __restrict__ P) {
    int i = blockIdx.x * 256 + threadIdx.x;
    int r = i >> 8, j = i & 255;
    float a = __bfloat162float(H[(size_t)r * 512 + j]);
    float g = __bfloat162float(H[(size_t)r * 512 + 256 + j]);
    P[i] = __float2bfloat16(a * gelu_exact(g));
}

// ---------------- final cast ----------------
__global__ __launch_bounds__(256) void k_cast_out(const float* __restrict__ X,
                                                  void* __restrict__ out,
                                                  const int* __restrict__ flag) {
    const int bf = *flag;
    int i = blockIdx.x * 256 + threadIdx.x;
    if (bf) ((bf16*)out)[i] = __float2bfloat16(X[i]);
    else    ((float*)out)[i] = X[i];
}

// =====================================================================
extern "C" void kernel_launch(void* const* d_in, const int* in_sizes, int n_in,
                              void* d_out, int out_size, void* d_ws, size_t ws_size,
                              hipStream_t stream) {
    const void* x       = d_in[0];
    const void* x_cont  = d_in[1];
    const void* c_ln1_g = d_in[2];
    const void* c_ln1_b = d_in[3];
    const void* c_wqkv  = d_in[4];
    const void* c_wo_w  = d_in[5];
    const void* c_wo_b  = d_in[6];
    const void* c_ln2_g = d_in[7];
    const void* c_ln2_b = d_in[8];
    const void* c_w1    = d_in[9];
    const void* c_b1    = d_in[10];
    const void* c_w2    = d_in[11];
    const void* c_b2    = d_in[12];
    const void* r_ln1_g = d_in[13];
    const void* r_ln1_b = d_in[14];
    const void* r_wqkv  = d_in[15];
    const void* r_wo_w  = d_in[16];
    const void* r_wo_b  = d_in[17];
    const void* r_ln2_g = d_in[18];
    const void* r_ln2_b = d_in[19];
    const void* r_w1    = d_in[20];
    const void* r_b1    = d_in[21];
    const void* r_w2    = d_in[22];
    const void* r_b2    = d_in[23];

    const size_t NX = (size_t)BD * NF * DIMC;        // 4,194,304
    float* X   = (float*)d_ws;
    float* XN  = X   + NX;
    float* ACC = XN  + NX;
    bf16* XNh  = (bf16*)(ACC + NX);
    bf16* WtR  = XNh + NX;                            // <=2048x2048
    bf16* WcQ  = WtR + (size_t)2048 * 2048;           // 1536x64
    bf16* WcO  = WcQ + 98304;                         // 64x512
    bf16* Wc1  = WcO + 32768;                         // 512x64
    bf16* Wc2  = Wc1 + 32768;                         // 64x256
    bf16* Sc   = Wc2 + 16384;                         // scratch union base

    // col block overlays:
    bf16*  OhC  = Sc;                                         // [0, 64 MiB)
    float* GpCW = (float*)((char*)Sc + 67108864);             // col-wo partials, KS=2 (33.5MB)
    bf16*  H1   = Sc;                                         // [0, 64 MiB) (OhC dead)
    bf16*  Pc   = Sc + 33554432;                              // [64, 96 MiB)
    float* GpC2 = (float*)Sc;                                 // col-w2 partials, KS=4 (67MB; H1 dead)
    // row block overlays:
    bf16*  QKVhR = Sc;                                        // 6.3MB
    bf16*  VtR   = QKVhR + 3145728;                           // 2.1MB
    bf16*  OhR   = VtR + 1048576;                             // 2.1MB
    bf16*  PmR   = OhR + 1048576;                             // 4.2MB
    float* Hrow  = (float*)(PmR + 2097152);                   // 16.8MB (ends 31.5MB)
    float* GpR   = (float*)((char*)Sc + 33554432);            // row partials (<=67MB, ends 96 MiB)
    float* MLp   = GpR + (size_t)4 * 1048576;                 // flash m/l (1MB)

    char* scEnd = (char*)Sc + 100663296;                      // 96 MiB
    int*  flag  = (int*)scEnd;
    const size_t need = (size_t)(scEnd + 64 - (char*)d_ws);
    if (ws_size < need) return;

    k_detect<<<1, 64, 0, stream>>>(x, flag);
    k_concat<<<16384, 256, 0, stream>>>(x, x_cont, X, flag);

    for (int d = 0; d < 4; ++d) {
        // ================= col block =================
        k_ln64<<<16384, 256, 0, stream>>>(X, XN, XNh, c_ln1_g, c_ln1_b, (size_t)d * 64, flag);
        k_castT<<<dim3(2, 48), 256, 0, stream>>>(c_wqkv, (size_t)d * 64 * 1536, 64, 1536, WcQ, flag);
        k_col_qkv_attn<<<4096, 256, 0, stream>>>(XNh, WcQ, OhC);
        // ACC = OhC @ c_wo_w + c_wo_b + XN  (split-K=2)
        k_castT<<<dim3(16, 2), 256, 0, stream>>>(c_wo_w, (size_t)d * 512 * 64, 512, 64, WcO, flag);
        k_mfma_sk<4, 1><<<dim3(1, 256, 2), 256, 0, stream>>>(
            65536, 64, 256, OhC, 512, WcO, 512, GpCW, 4194304);
        k_combine<false><<<16384, 256, 0, stream>>>(
            2, GpCW, 4194304, 64, ACC, c_wo_b, (size_t)d * 64, XN, flag);
        k_ln64<<<16384, 256, 0, stream>>>(ACC, XN, XNh, c_ln2_g, c_ln2_b, (size_t)d * 64, flag);
        // H1 = XNh @ c_w1 + c_b1
        k_castT<<<dim3(2, 16), 256, 0, stream>>>(c_w1, (size_t)d * 64 * 512, 64, 512, Wc1, flag);
        k_mfma<2, 2, true><<<dim3(4, 512, 1), 256, 0, stream>>>(
            65536, 512, 64, XNh, 64, 0, Wc1, 64, 0,
            H1, 512, 0, 1.0f, c_b1, (size_t)d * 512, nullptr, 0, flag);
        k_geglu_col<<<65536, 256, 0, stream>>>(H1, Pc);
        // X = Pc @ c_w2 + c_b2 + XN  (split-K=4)
        k_castT<<<dim3(8, 2), 256, 0, stream>>>(c_w2, (size_t)d * 256 * 64, 256, 64, Wc2, flag);
        k_mfma_sk<4, 1><<<dim3(1, 256, 4), 256, 0, stream>>>(
            65536, 64, 64, Pc, 256, Wc2, 256, GpC2, 4194304);
        k_combine<false><<<16384, 256, 0, stream>>>(
            4, GpC2, 4194304, 64, X, c_b2, (size_t)d * 64, XN, flag);

        // ================= row block =================
        k_ln_row<<<BD, 256, 0, stream>>>(X, XN, XNh, r_ln1_g, r_ln1_b, (size_t)d * DROW, flag);
        // QKVhR = XNh @ r_wqkv  (split-K=4)
        k_castT<<<dim3(64, 48), 256, 0, stream>>>(r_wqkv, (size_t)d * 2048 * 1536, 2048, 1536, WtR, flag);
        k_mfma_sk<2, 2><<<dim3(12, 16, 4), 256, 0, stream>>>(
            2048, 1536, 512, XNh, 2048, WtR, 2048, GpR, 3145728);
        k_combine<true><<<12288, 256, 0, stream>>>(
            4, GpR, 3145728, 1536, QKVhR, nullptr, 0, nullptr, flag);
        k_transpose_bf<<<dim3(64, 16), 256, 0, stream>>>(QKVhR + 1024, 1536, 2048, 512, VtR);
        // flash attention (K-split z=4) + combine
        k_flash_row<<<dim3(32, 8, 4), 256, 0, stream>>>(QKVhR, VtR, GpR, MLp);
        k_flash_combine<<<4096, 256, 0, stream>>>(GpR, MLp, OhR);
        // ACC = OhR @ r_wo_w + r_wo_b + XN  (split-K=4)
        k_castT<<<dim3(16, 64), 256, 0, stream>>>(r_wo_w, (size_t)d * 512 * 2048, 512, 2048, WtR, flag);
        k_mfma_sk<2, 2><<<dim3(16, 16, 4), 256, 0, stream>>>(
            2048, 2048, 128, OhR, 512, WtR, 512, GpR, 4194304);
        k_combine<false><<<16384, 256, 0, stream>>>(
            4, GpR, 4194304, 2048, ACC, r_wo_b, (size_t)d * DROW, XN, flag);
        k_ln_row<<<BD, 256, 0, stream>>>(ACC, XN, XNh, r_ln2_g, r_ln2_b, (size_t)d * DROW, flag);
        // Hrow = XNh @ r_w1 + r_b1  (split-K=4)
        k_castT<<<dim3(64, 64), 256, 0, stream>>>(r_w1, (size_t)d * 2048 * 2048, 2048, 2048, WtR, flag);
        k_mfma_sk<2, 2><<<dim3(16, 16, 4), 256, 0, stream>>>(
            2048, 2048, 512, XNh, 2048, WtR, 2048, GpR, 4194304);
        k_combine<false><<<16384, 256, 0, stream>>>(
            4, GpR, 4194304, 2048, Hrow, r_b1, (size_t)d * 2048, nullptr, flag);
        k_geglu_row<<<8192, 256, 0, stream>>>(Hrow, PmR);
        // X = PmR @ r_w2 + r_b2 + XN  (split-K=4)
        k_castT<<<dim3(32, 64), 256, 0, stream>>>(r_w2, (size_t)d * 1024 * 2048, 1024, 2048, WtR, flag);
        k_mfma_sk<2, 2><<<dim3(16, 16, 4), 256, 0, stream>>>(
            2048, 2048, 256, PmR, 1024, WtR, 1024, GpR, 4194304);
        k_combine<false><<<16384, 256, 0, stream>>>(
            4, GpR, 4194304, 2048, X, r_b2, (size_t)d * DROW, XN, flag);
    }

    k_cast_out<<<16384, 256, 0, stream>>>(X, d_out, flag);
}